// Round 8
// baseline (339.270 us; speedup 1.0000x reference)
//
#include <hip/hip_runtime.h>
#include <hip/hip_bf16.h>
#include <math.h>

// ---------------------------------------------------------------------------
// GATv2 policy net: 2x GATv2 layer (H=2, C=32, share_weights) + edge MLP.
// CSR build = bucketed counting sort (128 nodes/bucket), LDS counting.
// Attention is two-phase:
//   wgt  (edge-parallel): 16 edges/wave, lane(m,quad) covers 8 channels of
//        each head; 2-hop cross-quad reduce; ONE exp instruction per 16 edges.
//        Writes {w0,w1,srcbits} per edge.
//   aggw (node-parallel, lane=channel): pure weighted gather-sum + ELU.
// Layer-0 z is recomputed from x (input dim 2) everywhere - no z0 kernel.
// Unnormalized softmax (clamp 60) - exp cannot overflow; same math.
// Fusions: init+bfrag; easum+bhist; gvec inside 2nd mfma_gemm64.
// ---------------------------------------------------------------------------

typedef __attribute__((ext_vector_type(8))) short short8;
typedef __attribute__((ext_vector_type(4))) float f32x4;

#define BSH 7               // 128 nodes per bucket
#define CH 4096             // edges per block in bhist/phaseA

template <int IMM>
__device__ __forceinline__ float swz(float x) {
    return __int_as_float(__builtin_amdgcn_ds_swizzle(__float_as_int(x), IMM));
}

template <int CTRL>
__device__ __forceinline__ float dpp_add(float p) {
    int t = __builtin_amdgcn_update_dpp(0, __float_as_int(p), CTRL, 0xF, 0xF, true);
    return p + __int_as_float(t);
}

// truncating fp32 -> (hi, lo) bf16 split
__device__ __forceinline__ short2 bsplit(float x) {
    unsigned u = __float_as_uint(x);
    short hi = (short)(u >> 16);
    float hif = __uint_as_float(u & 0xFFFF0000u);
    short lo = (short)(__float_as_uint(x - hif) >> 16);
    return make_short2(hi, lo);
}

// ---- setup: blocks 0,1 = bfrag (split-bf16 B fragments); block 2 = zeroing --
// Bf layout (shorts): [((s*4+nt)*2+part)*512 + lane*8 + j]
__global__ __launch_bounds__(512) void setup_kernel(const float* __restrict__ W1,
                                                    const float* __restrict__ Wm1,
                                                    short* __restrict__ BfW1,
                                                    short* __restrict__ BfWm,
                                                    int* __restrict__ bucket_base,
                                                    float* __restrict__ easum, int nbuck) {
    if (blockIdx.x == 2) {
        for (int i = threadIdx.x; i <= nbuck; i += 512) bucket_base[i] = 0;
        if (threadIdx.x < 2) easum[threadIdx.x] = 0.f;
        return;
    }
    int snt = threadIdx.x >> 6;
    int lane = threadIdx.x & 63;
    int s = snt >> 2, nt = snt & 3;
    int col = nt * 16 + (lane & 15);
    short* Bf = blockIdx.x == 0 ? BfW1 : BfWm;
#pragma unroll
    for (int j = 0; j < 8; ++j) {
        int k = s * 32 + (lane >> 4) * 8 + j;
        float v;
        if (blockIdx.x == 0) {
            v = W1[k * 64 + col];
        } else {
            v = (col < 32) ? Wm1[k * 32 + col] : Wm1[(64 + k) * 32 + (col - 32)];
        }
        short2 t = bsplit(v);
        Bf[(snt * 2 + 0) * 512 + lane * 8 + j] = t.x;
        Bf[(snt * 2 + 1) * 512 + lane * 8 + j] = t.y;
    }
}

// ---- pre: easum (block-tree + 2 atomics/block) fused with bucket histogram --
__global__ __launch_bounds__(256) void pre_kernel(const int* __restrict__ ei,
                                                  const float2* __restrict__ ea,
                                                  int* __restrict__ bucket_base,
                                                  float* __restrict__ easum,
                                                  int E, int EP, int nbuck) {
    extern __shared__ int lcnt[];
    __shared__ float r0[4], r1[4];
    int tid = threadIdx.x;
    for (int i = tid; i < nbuck; i += 256) lcnt[i] = 0;
    // easum partial (registers, no LDS dependency)
    float s0 = 0.f, s1 = 0.f;
    int estride = gridDim.x * 256;
    for (int e = blockIdx.x * 256 + tid; e < E; e += estride) {
        float2 v = ea[e];
        s0 += v.x; s1 += v.y;
    }
#pragma unroll
    for (int o = 32; o >= 1; o >>= 1) {
        s0 += __shfl_xor(s0, o);
        s1 += __shfl_xor(s1, o);
    }
    int wave = tid >> 6;
    if ((tid & 63) == 0) { r0[wave] = s0; r1[wave] = s1; }
    __syncthreads();                       // lcnt zeroed, r0/r1 visible
    int base = blockIdx.x * CH;
    int end = min(base + CH, EP);
    for (int i = base + tid; i < end; i += 256) {
        int d = (i < E) ? ei[E + i] : (i - E);
        atomicAdd(&lcnt[d >> BSH], 1);
    }
    __syncthreads();
    if (tid == 0) {
        atomicAdd(&easum[0], r0[0] + r0[1] + r0[2] + r0[3]);
        atomicAdd(&easum[1], r1[0] + r1[1] + r1[2] + r1[3]);
    }
    for (int i = tid; i < nbuck; i += 256) {
        int c = lcnt[i];
        if (c) atomicAdd(&bucket_base[i], c);
    }
}

// single-block exclusive scan of bucket counts
__global__ __launch_bounds__(256) void bscan_kernel(int* __restrict__ bucket_base,
                                                    int* __restrict__ bucket_cursor,
                                                    int* __restrict__ row_ptr,
                                                    int N, int nbuck) {
    __shared__ int sm[256];
    int tid = threadIdx.x;
    int K = (nbuck + 255) / 256;
    int b0 = tid * K;
    int local = 0;
    for (int k = 0; k < K; ++k) {
        int b = b0 + k;
        if (b < nbuck) local += bucket_base[b];
    }
    sm[tid] = local;
    __syncthreads();
    for (int st = 1; st < 256; st <<= 1) {
        int v = sm[tid];
        int a = (tid >= st) ? sm[tid - st] : 0;
        __syncthreads();
        sm[tid] = v + a;
        __syncthreads();
    }
    int run = (tid == 0) ? 0 : sm[tid - 1];
    for (int k = 0; k < K; ++k) {
        int b = b0 + k;
        if (b < nbuck) {
            int c = bucket_base[b];
            bucket_base[b] = run;
            bucket_cursor[b] = run;
            run += c;
        }
    }
    if (tid == 255) {
        bucket_base[nbuck] = sm[255];
        row_ptr[N] = sm[255];
    }
}

// partition edges into bucket-contiguous staged[]; records {src, eax, eay, dst}
__global__ __launch_bounds__(256) void phaseA_kernel(const int* __restrict__ ei,
                                                     const float2* __restrict__ ea,
                                                     const float* __restrict__ easum,
                                                     int* __restrict__ bucket_cursor,
                                                     float4* __restrict__ staged,
                                                     int E, int EP, int nbuck) {
    extern __shared__ int sm[];          // lcnt[nbuck] then lbase[nbuck]
    int* lcnt = sm;
    int* lbase = sm + nbuck;
    int tid = threadIdx.x;
    for (int i = tid; i < nbuck; i += 256) lcnt[i] = 0;
    __syncthreads();
    int base = blockIdx.x * CH;
    int end = min(base + CH, EP);
    for (int i = base + tid; i < end; i += 256) {
        int d = (i < E) ? ei[E + i] : (i - E);
        atomicAdd(&lcnt[d >> BSH], 1);
    }
    __syncthreads();
    for (int i = tid; i < nbuck; i += 256) {
        int c = lcnt[i];
        lbase[i] = c ? atomicAdd(&bucket_cursor[i], c) : 0;
        lcnt[i] = 0;
    }
    __syncthreads();
    float inv = 1.f / (float)E;
    float m0 = easum[0] * inv, m1 = easum[1] * inv;
    for (int i = base + tid; i < end; i += 256) {
        int s, d; float ex, ey;
        if (i < E) {
            s = ei[i]; d = ei[E + i];
            float2 v = ea[i]; ex = v.x; ey = v.y;
        } else {
            s = d = i - E; ex = m0; ey = m1;
        }
        int b = d >> BSH;
        int pos = lbase[b] + atomicAdd(&lcnt[b], 1);
        staged[pos] = make_float4(__int_as_float(s), ex, ey, __int_as_float(d));
    }
}

// per bucket: per-node LDS count + scan -> row_ptr; exact CSR placement
__global__ __launch_bounds__(256) void phaseB_kernel(const float4* __restrict__ staged,
                                                     const int* __restrict__ bucket_base,
                                                     int* __restrict__ row_ptr,
                                                     float4* __restrict__ recs, int N) {
    __shared__ int cnt128[128];
    __shared__ int offs[128];
    int b = blockIdx.x;
    int n0 = b << BSH;
    int tid = threadIdx.x;
    if (tid < 128) cnt128[tid] = 0;
    __syncthreads();
    int begs = bucket_base[b];
    int ends = bucket_base[b + 1];
    for (int i = begs + tid; i < ends; i += 256) {
        int d = __float_as_int(staged[i].w);
        atomicAdd(&cnt128[d - n0], 1);
    }
    __syncthreads();
    if (tid < 128) offs[tid] = cnt128[tid];
    __syncthreads();
    for (int st = 1; st < 128; st <<= 1) {
        int v = 0;
        if (tid < 128) {
            v = offs[tid];
            if (tid >= st) v += offs[tid - st];
        }
        __syncthreads();
        if (tid < 128) offs[tid] = v;
        __syncthreads();
    }
    if (tid < 128) {
        int excl = begs + offs[tid] - cnt128[tid];
        int node = n0 + tid;
        if (node < N) row_ptr[node] = excl;
        offs[tid] = excl;
    }
    __syncthreads();
    for (int i = begs + tid; i < ends; i += 256) {
        float4 r = staged[i];
        int d = __float_as_int(r.w);
        int pos = atomicAdd(&offs[d - n0], 1);
        recs[pos] = r;
    }
}

// ---- wgt1: edge-parallel attention weights for layer 1 (z gathered) ---------
// 16 edges per wave; lane(m=lane&15, quad) covers channels quad*8..+7 of
// head0 (c0) and head1 (c1=c0+32). 2-hop reduce over quads; 1 exp inst/16edges.
__global__ __launch_bounds__(256) void wgt1_kernel(const float* __restrict__ z,
                                                   const float4* __restrict__ recs,
                                                   const float* __restrict__ We,
                                                   const float* __restrict__ att,
                                                   float4* __restrict__ wbuf, int EP) {
    int lane = threadIdx.x & 63;
    int m = lane & 15, quad = lane >> 4;
    int c0 = quad * 8, c1 = 32 + c0;
    float w0a[8], w1a[8], ata[8], w0b[8], w1b[8], atb[8];
#pragma unroll
    for (int j = 0; j < 8; ++j) {
        w0a[j] = We[c0 + j];  w1a[j] = We[64 + c0 + j];  ata[j] = att[c0 + j];
        w0b[j] = We[c1 + j];  w1b[j] = We[64 + c1 + j];  atb[j] = att[c1 + j];
    }
    int ntiles = (EP + 15) >> 4;
    int wid = (blockIdx.x * blockDim.x + threadIdx.x) >> 6;
    int nw = (gridDim.x * blockDim.x) >> 6;
    for (int t = wid; t < ntiles; t += nw) {
        int e = t * 16 + m;
        int ec = e < EP ? e : EP - 1;
        float4 r = recs[ec];
        int s = __float_as_int(r.x);
        int d = __float_as_int(r.w);
        const float* zs = z + (size_t)s * 64;
        const float* zd = z + (size_t)d * 64;
        float4 sa0 = *(const float4*)(zs + c0), sa1 = *(const float4*)(zs + c0 + 4);
        float4 sb0 = *(const float4*)(zs + c1), sb1 = *(const float4*)(zs + c1 + 4);
        float4 da0 = *(const float4*)(zd + c0), da1 = *(const float4*)(zd + c0 + 4);
        float4 db0 = *(const float4*)(zd + c1), db1 = *(const float4*)(zd + c1 + 4);
        float sva[8] = {sa0.x, sa0.y, sa0.z, sa0.w, sa1.x, sa1.y, sa1.z, sa1.w};
        float svb[8] = {sb0.x, sb0.y, sb0.z, sb0.w, sb1.x, sb1.y, sb1.z, sb1.w};
        float dva[8] = {da0.x, da0.y, da0.z, da0.w, da1.x, da1.y, da1.z, da1.w};
        float dvb[8] = {db0.x, db0.y, db0.z, db0.w, db1.x, db1.y, db1.z, db1.w};
        float P0 = 0.f, P1 = 0.f;
#pragma unroll
        for (int j = 0; j < 8; ++j) {
            float t0 = dva[j] + sva[j] + fmaf(r.y, w0a[j], r.z * w1a[j]);
            t0 = fmaxf(t0, 0.2f * t0);
            P0 = fmaf(t0, ata[j], P0);
            float t1 = dvb[j] + svb[j] + fmaf(r.y, w0b[j], r.z * w1b[j]);
            t1 = fmaxf(t1, 0.2f * t1);
            P1 = fmaf(t1, atb[j], P1);
        }
        P0 += swz<0x401F>(P0);             // quad pair (xor 16)
        P1 += swz<0x401F>(P1);
        P0 += __shfl_xor(P0, 32);          // cross-half (xor 32)
        P1 += __shfl_xor(P1, 32);
        float w0 = __expf(fminf(P0, 60.f));
        float w1 = __expf(fminf(P1, 60.f));
        if (lane < 16 && e < EP) wbuf[e] = make_float4(w0, w1, r.x, 0.f);
    }
}

// ---- wgt0: same, layer 0 - z recomputed from x via W0 (input dim 2) ---------
__global__ __launch_bounds__(256) void wgt0_kernel(const float2* __restrict__ x,
                                                   const float* __restrict__ W0,
                                                   const float* __restrict__ b0,
                                                   const float4* __restrict__ recs,
                                                   const float* __restrict__ We,
                                                   const float* __restrict__ att,
                                                   float4* __restrict__ wbuf, int EP) {
    int lane = threadIdx.x & 63;
    int m = lane & 15, quad = lane >> 4;
    int c0 = quad * 8, c1 = 32 + c0;
    float w0a[8], w1a[8], ata[8], w0b[8], w1b[8], atb[8];
    float Wxa[8], Wya[8], bca[8], Wxb[8], Wyb[8], bcb[8];
#pragma unroll
    for (int j = 0; j < 8; ++j) {
        w0a[j] = We[c0 + j];  w1a[j] = We[64 + c0 + j];  ata[j] = att[c0 + j];
        w0b[j] = We[c1 + j];  w1b[j] = We[64 + c1 + j];  atb[j] = att[c1 + j];
        Wxa[j] = W0[c0 + j];  Wya[j] = W0[64 + c0 + j];  bca[j] = b0[c0 + j];
        Wxb[j] = W0[c1 + j];  Wyb[j] = W0[64 + c1 + j];  bcb[j] = b0[c1 + j];
    }
    int ntiles = (EP + 15) >> 4;
    int wid = (blockIdx.x * blockDim.x + threadIdx.x) >> 6;
    int nw = (gridDim.x * blockDim.x) >> 6;
    for (int t = wid; t < ntiles; t += nw) {
        int e = t * 16 + m;
        int ec = e < EP ? e : EP - 1;
        float4 r = recs[ec];
        int s = __float_as_int(r.x);
        int d = __float_as_int(r.w);
        float2 xs = x[s];
        float2 xd = x[d];
        float P0 = 0.f, P1 = 0.f;
#pragma unroll
        for (int j = 0; j < 8; ++j) {
            float zs = fmaf(xs.x, Wxa[j], fmaf(xs.y, Wya[j], bca[j]));
            float zd = fmaf(xd.x, Wxa[j], fmaf(xd.y, Wya[j], bca[j]));
            float t0 = zd + zs + fmaf(r.y, w0a[j], r.z * w1a[j]);
            t0 = fmaxf(t0, 0.2f * t0);
            P0 = fmaf(t0, ata[j], P0);
            float zs1 = fmaf(xs.x, Wxb[j], fmaf(xs.y, Wyb[j], bcb[j]));
            float zd1 = fmaf(xd.x, Wxb[j], fmaf(xd.y, Wyb[j], bcb[j]));
            float t1 = zd1 + zs1 + fmaf(r.y, w0b[j], r.z * w1b[j]);
            t1 = fmaxf(t1, 0.2f * t1);
            P1 = fmaf(t1, atb[j], P1);
        }
        P0 += swz<0x401F>(P0);
        P1 += swz<0x401F>(P1);
        P0 += __shfl_xor(P0, 32);
        P1 += __shfl_xor(P1, 32);
        float w0 = __expf(fminf(P0, 60.f));
        float w1 = __expf(fminf(P1, 60.f));
        if (lane < 16 && e < EP) wbuf[e] = make_float4(w0, w1, r.x, 0.f);
    }
}

// ---- aggw1: node-parallel weighted sum (layer 1) ----------------------------
__global__ __launch_bounds__(256) void aggw1_kernel(const float* __restrict__ z,
                                                    const int* __restrict__ row_ptr,
                                                    const float4* __restrict__ wbuf,
                                                    const float* __restrict__ bias,
                                                    float* __restrict__ hout, int N) {
    int gtid = blockIdx.x * blockDim.x + threadIdx.x;
    int n = gtid >> 6;
    if (n >= N) return;
    n = __builtin_amdgcn_readfirstlane(n);
    int lane = threadIdx.x & 63;
    int head = lane >> 5;
    int beg = row_ptr[n], end = row_ptr[n + 1];
    float ll[4] = {0.f, 0.f, 0.f, 0.f};
    float aa[4] = {0.f, 0.f, 0.f, 0.f};
    int i = beg;
    for (; i + 8 <= end; i += 8) {
        float w[8], zs[8];
#pragma unroll
        for (int k = 0; k < 8; ++k) {
            float4 r = wbuf[i + k];
            int s = __builtin_amdgcn_readfirstlane(__float_as_int(r.z));
            w[k] = head ? r.y : r.x;
            zs[k] = z[(size_t)s * 64 + lane];
        }
#pragma unroll
        for (int k = 0; k < 8; ++k) {
            ll[k & 3] += w[k];
            aa[k & 3] = fmaf(w[k], zs[k], aa[k & 3]);
        }
    }
    for (; i < end; ++i) {
        float4 r = wbuf[i];
        int s = __builtin_amdgcn_readfirstlane(__float_as_int(r.z));
        float w = head ? r.y : r.x;
        float zs = z[(size_t)s * 64 + lane];
        ll[0] += w;
        aa[0] = fmaf(w, zs, aa[0]);
    }
    float l = (ll[0] + ll[1]) + (ll[2] + ll[3]);
    float a = (aa[0] + aa[1]) + (aa[2] + aa[3]);
    float v = a / (l + 1e-16f) + bias[lane];
    v = (v > 0.f) ? v : expm1f(v);
    hout[(size_t)n * 64 + lane] = v;
}

// ---- aggw0: node-parallel weighted sum (layer 0, zs from x) -----------------
__global__ __launch_bounds__(256) void aggw0_kernel(const float2* __restrict__ x,
                                                    const float* __restrict__ W0,
                                                    const float* __restrict__ b0,
                                                    const int* __restrict__ row_ptr,
                                                    const float4* __restrict__ wbuf,
                                                    const float* __restrict__ bias,
                                                    float* __restrict__ hout, int N) {
    int gtid = blockIdx.x * blockDim.x + threadIdx.x;
    int n = gtid >> 6;
    if (n >= N) return;
    n = __builtin_amdgcn_readfirstlane(n);
    int lane = threadIdx.x & 63;
    int head = lane >> 5;
    float W0a = W0[lane], W0b = W0[64 + lane], b0c = b0[lane];
    int beg = row_ptr[n], end = row_ptr[n + 1];
    float ll[4] = {0.f, 0.f, 0.f, 0.f};
    float aa[4] = {0.f, 0.f, 0.f, 0.f};
    int i = beg;
    for (; i + 8 <= end; i += 8) {
        float w[8], zs[8];
#pragma unroll
        for (int k = 0; k < 8; ++k) {
            float4 r = wbuf[i + k];
            int s = __builtin_amdgcn_readfirstlane(__float_as_int(r.z));
            float2 xs = x[s];
            w[k] = head ? r.y : r.x;
            zs[k] = fmaf(xs.x, W0a, fmaf(xs.y, W0b, b0c));
        }
#pragma unroll
        for (int k = 0; k < 8; ++k) {
            ll[k & 3] += w[k];
            aa[k & 3] = fmaf(w[k], zs[k], aa[k & 3]);
        }
    }
    for (; i < end; ++i) {
        float4 r = wbuf[i];
        int s = __builtin_amdgcn_readfirstlane(__float_as_int(r.z));
        float2 xs = x[s];
        float w = head ? r.y : r.x;
        float zs = fmaf(xs.x, W0a, fmaf(xs.y, W0b, b0c));
        ll[0] += w;
        aa[0] = fmaf(w, zs, aa[0]);
    }
    float l = (ll[0] + ll[1]) + (ll[2] + ll[3]);
    float a = (aa[0] + aa[1]) + (aa[2] + aa[3]);
    float v = a / (l + 1e-16f) + bias[lane];
    v = (v > 0.f) ? v : expm1f(v);
    hout[(size_t)n * 64 + lane] = v;
}

// ---- out[N x 64] = h[N x 64] @ B[64 x 64] (+ bias), split-bf16 MFMA ---------
// optional gvec fold: block 0 threads 0-31 also compute the goal vector.
__global__ __launch_bounds__(256) void mfma_gemm64(const float* __restrict__ h,
                                                   const short* __restrict__ Bf,
                                                   const float* __restrict__ bias,
                                                   float* __restrict__ out, int N,
                                                   const float* __restrict__ Wm1,
                                                   const float* __restrict__ bm1,
                                                   const int* __restrict__ dest,
                                                   float* __restrict__ gv) {
    int wave = threadIdx.x >> 6;
    int lane = threadIdx.x & 63;
    int n0 = blockIdx.x * 64 + wave * 16;
    if (n0 < N) {
        int m = lane & 15, quad = lane >> 4;
        int arow = n0 + m;
        if (arow > N - 1) arow = N - 1;
        f32x4 acc[4] = {{0.f, 0.f, 0.f, 0.f}, {0.f, 0.f, 0.f, 0.f},
                        {0.f, 0.f, 0.f, 0.f}, {0.f, 0.f, 0.f, 0.f}};
#pragma unroll
        for (int s = 0; s < 2; ++s) {
            const float* ap = h + (size_t)arow * 64 + s * 32 + quad * 8;
            float4 a0 = *(const float4*)ap;
            float4 a1 = *(const float4*)(ap + 4);
            short8 ahi, alo;
            short2 t;
            t = bsplit(a0.x); ahi[0] = t.x; alo[0] = t.y;
            t = bsplit(a0.y); ahi[1] = t.x; alo[1] = t.y;
            t = bsplit(a0.z); ahi[2] = t.x; alo[2] = t.y;
            t = bsplit(a0.w); ahi[3] = t.x; alo[3] = t.y;
            t = bsplit(a1.x); ahi[4] = t.x; alo[4] = t.y;
            t = bsplit(a1.y); ahi[5] = t.x; alo[5] = t.y;
            t = bsplit(a1.z); ahi[6] = t.x; alo[6] = t.y;
            t = bsplit(a1.w); ahi[7] = t.x; alo[7] = t.y;
#pragma unroll
            for (int nt = 0; nt < 4; ++nt) {
                const short* bp = Bf + ((s * 4 + nt) * 2) * 512 + lane * 8;
                short8 bhi = *(const short8*)bp;
                short8 blo = *(const short8*)(bp + 512);
                acc[nt] = __builtin_amdgcn_mfma_f32_16x16x32_bf16(ahi, bhi, acc[nt], 0, 0, 0);
                acc[nt] = __builtin_amdgcn_mfma_f32_16x16x32_bf16(ahi, blo, acc[nt], 0, 0, 0);
                acc[nt] = __builtin_amdgcn_mfma_f32_16x16x32_bf16(alo, bhi, acc[nt], 0, 0, 0);
            }
        }
#pragma unroll
        for (int nt = 0; nt < 4; ++nt) {
            int col = nt * 16 + m;
            float bj = bias ? bias[col] : 0.f;
#pragma unroll
            for (int r = 0; r < 4; ++r) {
                int orow = n0 + quad * 4 + r;
                if (orow < N) out[(size_t)orow * 64 + col] = acc[nt][r] + bj;
            }
        }
    }
    // gvec fold (reads h, independent of gemm output)
    if (gv && blockIdx.x == 0 && threadIdx.x < 32) {
        int dd = dest[0];
        int q = threadIdx.x;
        float acc2 = bm1[q];
        for (int k = 0; k < 64; ++k)
            acc2 = fmaf(h[(size_t)dd * 64 + k], Wm1[(128 + k) * 32 + q], acc2);
        gv[q] = acc2;
    }
}

// 8 lanes per edge; hsd[n*64+0:32]=hs, hsd[n*64+32:64]=hd
__global__ __launch_bounds__(256) void edge_mlp_kernel(
    const int* __restrict__ ei, const float2* __restrict__ ea,
    const float* __restrict__ hsd, const float* __restrict__ gvec,
    const float* __restrict__ WrowA, const float* __restrict__ WrowB,
    const float* __restrict__ Wm2, const float* __restrict__ bm2,
    float* __restrict__ out, int E) {
    int tid = blockIdx.x * blockDim.x + threadIdx.x;
    int e = tid >> 3;
    int j = tid & 7;
    if (e >= E) return;
    int s = ei[e], d = ei[E + e];
    float2 eav = ea[e];
    float4 a = *(const float4*)(hsd + (size_t)s * 64 + j * 4);
    float4 bv = *(const float4*)(hsd + (size_t)d * 64 + 32 + j * 4);
    float4 g = *(const float4*)(gvec + j * 4);
    float4 wa = *(const float4*)(WrowA + j * 4);
    float4 wb = *(const float4*)(WrowB + j * 4);
    float4 w2 = *(const float4*)(Wm2 + j * 4);
    float acc = 0.f, v;
    v = fmaf(eav.x, wa.x, fmaf(eav.y, wb.x, a.x + bv.x + g.x)); v = fmaxf(v, 0.f); acc = fmaf(v, w2.x, acc);
    v = fmaf(eav.x, wa.y, fmaf(eav.y, wb.y, a.y + bv.y + g.y)); v = fmaxf(v, 0.f); acc = fmaf(v, w2.y, acc);
    v = fmaf(eav.x, wa.z, fmaf(eav.y, wb.z, a.z + bv.z + g.z)); v = fmaxf(v, 0.f); acc = fmaf(v, w2.z, acc);
    v = fmaf(eav.x, wa.w, fmaf(eav.y, wb.w, a.w + bv.w + g.w)); v = fmaxf(v, 0.f); acc = fmaf(v, w2.w, acc);
    acc = dpp_add<0xB1>(acc);    // xor 1
    acc = dpp_add<0x4E>(acc);    // xor 2
    acc = dpp_add<0x141>(acc);   // xor 7 — closes the 8-group
    if (j == 0) out[e] = acc + bm2[0];
}

extern "C" void kernel_launch(void* const* d_in, const int* in_sizes, int n_in,
                              void* d_out, int out_size, void* d_ws, size_t ws_size,
                              hipStream_t stream) {
    const float* x     = (const float*)d_in[0];
    const int*   ei    = (const int*)d_in[1];
    const float* ea    = (const float*)d_in[2];
    const int*   dest  = (const int*)d_in[3];
    const float* W0    = (const float*)d_in[4];
    const float* b0    = (const float*)d_in[5];
    const float* We0   = (const float*)d_in[6];
    const float* att0  = (const float*)d_in[7];
    const float* bias0 = (const float*)d_in[8];
    const float* W1    = (const float*)d_in[9];
    const float* b1    = (const float*)d_in[10];
    const float* We1   = (const float*)d_in[11];
    const float* att1  = (const float*)d_in[12];
    const float* bias1 = (const float*)d_in[13];
    const float* Wm1   = (const float*)d_in[14];
    const float* bm1   = (const float*)d_in[15];
    const float* Wm2   = (const float*)d_in[16];
    const float* bm2   = (const float*)d_in[17];

    const int N = in_sizes[0] / 2;
    const int E = in_sizes[1] / 2;
    const int EP = E + N;
    const int nbuck = (N + 127) >> BSH;
    const int nchunk = (EP + CH - 1) / CH;

    char* ws = (char*)d_ws;
    size_t off = 0;
    auto alloc = [&](size_t bytes) -> void* {
        void* p = ws + off;
        off += bytes;
        off = (off + 255) & ~(size_t)255;
        return p;
    };
    int*    bucket_base   = (int*)alloc((size_t)(nbuck + 1) * 4);
    int*    bucket_cursor = (int*)alloc((size_t)nbuck * 4);
    int*    row_ptr       = (int*)alloc((size_t)(N + 1) * 4);
    // staged shares memory with zbuf (staged dead before gemm64 writes zbuf)
    size_t  shared_bytes  = (size_t)EP * 16 > (size_t)N * 256 ? (size_t)EP * 16
                                                              : (size_t)N * 256;
    float4* staged        = (float4*)alloc(shared_bytes);
    float4* recs          = (float4*)alloc((size_t)EP * 16);
    float4* wbuf          = (float4*)alloc((size_t)EP * 16);
    float*  hbuf          = (float*)alloc((size_t)N * 64 * 4);
    float*  easum         = (float*)alloc(8);
    float*  gvec          = (float*)alloc(32 * 4);
    short*  BfW1          = (short*)alloc(8192 * 2);
    short*  BfWm          = (short*)alloc(8192 * 2);
    float*  zbuf          = (float*)staged;
    float*  hsd           = zbuf;   // reuse: z1 dead after layer-1 aggregation

    dim3 blk(256);
    setup_kernel<<<3, 512, 0, stream>>>(W1, Wm1, BfW1, BfWm, bucket_base, easum, nbuck);
    pre_kernel<<<nchunk, blk, (size_t)nbuck * 4, stream>>>(ei, (const float2*)ea,
                                                           bucket_base, easum, E, EP, nbuck);
    bscan_kernel<<<1, blk, 0, stream>>>(bucket_base, bucket_cursor, row_ptr, N, nbuck);
    phaseA_kernel<<<nchunk, blk, (size_t)nbuck * 8, stream>>>(ei, (const float2*)ea, easum,
                                                              bucket_cursor, staged, E, EP, nbuck);
    phaseB_kernel<<<nbuck, blk, 0, stream>>>(staged, bucket_base, row_ptr, recs, N);
    wgt0_kernel<<<2048, blk, 0, stream>>>((const float2*)x, W0, b0, recs, We0, att0, wbuf, EP);
    aggw0_kernel<<<(N * 64 + 255) / 256, blk, 0, stream>>>((const float2*)x, W0, b0,
                                                           row_ptr, wbuf, bias0, hbuf, N);
    mfma_gemm64<<<(N + 63) / 64, blk, 0, stream>>>(hbuf, BfW1, b1, zbuf, N,
                                                   nullptr, nullptr, nullptr, nullptr);
    wgt1_kernel<<<2048, blk, 0, stream>>>(zbuf, recs, We1, att1, wbuf, EP);
    aggw1_kernel<<<(N * 64 + 255) / 256, blk, 0, stream>>>(zbuf, row_ptr, wbuf,
                                                           bias1, hbuf, N);
    mfma_gemm64<<<(N + 63) / 64, blk, 0, stream>>>(hbuf, BfWm, (const float*)nullptr, hsd, N,
                                                   Wm1, bm1, dest, gvec);
    edge_mlp_kernel<<<((size_t)E * 8 + 255) / 256, blk, 0, stream>>>(
        ei, (const float2*)ea, hsd, gvec,
        Wm1 + 192 * 32, Wm1 + 193 * 32, Wm2, bm2, (float*)d_out, E);
}

// Round 9
// 285.132 us; speedup vs baseline: 1.1899x; 1.1899x over previous
//
#include <hip/hip_runtime.h>
#include <hip/hip_bf16.h>
#include <math.h>

// ---------------------------------------------------------------------------
// GATv2 policy net: 2x GATv2 layer (H=2, C=32, share_weights) + edge MLP.
// CSR build = bucketed counting sort (128 nodes/bucket), LDS counting.
// agg kernels (fused attention+aggregation, wave/node, lane=channel):
//   batched transposed reduction - 8 edges/pass:
//     per edge: 3 hops (xor1,xor2,half-mirror) -> 8-lane group sums
//     select p[lane&7] (7 cndmask) -> one xor8(row_ror:8)+xor16 finish
//     ONE v_exp covers 8 edges x 2 heads; redistribute via 8 swizzles.
//   remainder handled by clamp+mask (no tail path).
// Layer-0 z recomputed from x (input dim 2) - no z0 kernel, 8B gathers.
// Unnormalized softmax (clamp 60): exp cannot overflow; same math.
// Fusions: init+bfrag (setup); easum+bhist (pre); gvec inside 2nd gemm.
// ---------------------------------------------------------------------------

typedef __attribute__((ext_vector_type(8))) short short8;
typedef __attribute__((ext_vector_type(4))) float f32x4;

#define BSH 7               // 128 nodes per bucket
#define CH 4096             // edges per block in pre/phaseA

template <int IMM>
__device__ __forceinline__ float swz(float x) {
    return __int_as_float(__builtin_amdgcn_ds_swizzle(__float_as_int(x), IMM));
}

template <int CTRL>
__device__ __forceinline__ float dpp_add(float p) {
    int t = __builtin_amdgcn_update_dpp(0, __float_as_int(p), CTRL, 0xF, 0xF, true);
    return p + __int_as_float(t);
}

// truncating fp32 -> (hi, lo) bf16 split
__device__ __forceinline__ short2 bsplit(float x) {
    unsigned u = __float_as_uint(x);
    short hi = (short)(u >> 16);
    float hif = __uint_as_float(u & 0xFFFF0000u);
    short lo = (short)(__float_as_uint(x - hif) >> 16);
    return make_short2(hi, lo);
}

// ---- setup: blocks 0,1 = bfrag (split-bf16 B fragments); block 2 = zeroing --
__global__ __launch_bounds__(512) void setup_kernel(const float* __restrict__ W1,
                                                    const float* __restrict__ Wm1,
                                                    short* __restrict__ BfW1,
                                                    short* __restrict__ BfWm,
                                                    int* __restrict__ bucket_base,
                                                    float* __restrict__ easum, int nbuck) {
    if (blockIdx.x == 2) {
        for (int i = threadIdx.x; i <= nbuck; i += 512) bucket_base[i] = 0;
        if (threadIdx.x < 2) easum[threadIdx.x] = 0.f;
        return;
    }
    int snt = threadIdx.x >> 6;
    int lane = threadIdx.x & 63;
    int s = snt >> 2, nt = snt & 3;
    int col = nt * 16 + (lane & 15);
    short* Bf = blockIdx.x == 0 ? BfW1 : BfWm;
#pragma unroll
    for (int j = 0; j < 8; ++j) {
        int k = s * 32 + (lane >> 4) * 8 + j;
        float v;
        if (blockIdx.x == 0) {
            v = W1[k * 64 + col];
        } else {
            v = (col < 32) ? Wm1[k * 32 + col] : Wm1[(64 + k) * 32 + (col - 32)];
        }
        short2 t = bsplit(v);
        Bf[(snt * 2 + 0) * 512 + lane * 8 + j] = t.x;
        Bf[(snt * 2 + 1) * 512 + lane * 8 + j] = t.y;
    }
}

// ---- pre: easum (block-tree + 2 atomics/block) fused with bucket histogram --
__global__ __launch_bounds__(256) void pre_kernel(const int* __restrict__ ei,
                                                  const float2* __restrict__ ea,
                                                  int* __restrict__ bucket_base,
                                                  float* __restrict__ easum,
                                                  int E, int EP, int nbuck) {
    extern __shared__ int lcnt[];
    __shared__ float r0[4], r1[4];
    int tid = threadIdx.x;
    for (int i = tid; i < nbuck; i += 256) lcnt[i] = 0;
    float s0 = 0.f, s1 = 0.f;
    int estride = gridDim.x * 256;
    for (int e = blockIdx.x * 256 + tid; e < E; e += estride) {
        float2 v = ea[e];
        s0 += v.x; s1 += v.y;
    }
#pragma unroll
    for (int o = 32; o >= 1; o >>= 1) {
        s0 += __shfl_xor(s0, o);
        s1 += __shfl_xor(s1, o);
    }
    int wave = tid >> 6;
    if ((tid & 63) == 0) { r0[wave] = s0; r1[wave] = s1; }
    __syncthreads();
    int base = blockIdx.x * CH;
    int end = min(base + CH, EP);
    for (int i = base + tid; i < end; i += 256) {
        int d = (i < E) ? ei[E + i] : (i - E);
        atomicAdd(&lcnt[d >> BSH], 1);
    }
    __syncthreads();
    if (tid == 0) {
        atomicAdd(&easum[0], r0[0] + r0[1] + r0[2] + r0[3]);
        atomicAdd(&easum[1], r1[0] + r1[1] + r1[2] + r1[3]);
    }
    for (int i = tid; i < nbuck; i += 256) {
        int c = lcnt[i];
        if (c) atomicAdd(&bucket_base[i], c);
    }
}

// single-block exclusive scan of bucket counts
__global__ __launch_bounds__(256) void bscan_kernel(int* __restrict__ bucket_base,
                                                    int* __restrict__ bucket_cursor,
                                                    int* __restrict__ row_ptr,
                                                    int N, int nbuck) {
    __shared__ int sm[256];
    int tid = threadIdx.x;
    int K = (nbuck + 255) / 256;
    int b0 = tid * K;
    int local = 0;
    for (int k = 0; k < K; ++k) {
        int b = b0 + k;
        if (b < nbuck) local += bucket_base[b];
    }
    sm[tid] = local;
    __syncthreads();
    for (int st = 1; st < 256; st <<= 1) {
        int v = sm[tid];
        int a = (tid >= st) ? sm[tid - st] : 0;
        __syncthreads();
        sm[tid] = v + a;
        __syncthreads();
    }
    int run = (tid == 0) ? 0 : sm[tid - 1];
    for (int k = 0; k < K; ++k) {
        int b = b0 + k;
        if (b < nbuck) {
            int c = bucket_base[b];
            bucket_base[b] = run;
            bucket_cursor[b] = run;
            run += c;
        }
    }
    if (tid == 255) {
        bucket_base[nbuck] = sm[255];
        row_ptr[N] = sm[255];
    }
}

// partition edges into bucket-contiguous staged[]; records {src, eax, eay, dst}
__global__ __launch_bounds__(256) void phaseA_kernel(const int* __restrict__ ei,
                                                     const float2* __restrict__ ea,
                                                     const float* __restrict__ easum,
                                                     int* __restrict__ bucket_cursor,
                                                     float4* __restrict__ staged,
                                                     int E, int EP, int nbuck) {
    extern __shared__ int sm[];          // lcnt[nbuck] then lbase[nbuck]
    int* lcnt = sm;
    int* lbase = sm + nbuck;
    int tid = threadIdx.x;
    for (int i = tid; i < nbuck; i += 256) lcnt[i] = 0;
    __syncthreads();
    int base = blockIdx.x * CH;
    int end = min(base + CH, EP);
    for (int i = base + tid; i < end; i += 256) {
        int d = (i < E) ? ei[E + i] : (i - E);
        atomicAdd(&lcnt[d >> BSH], 1);
    }
    __syncthreads();
    for (int i = tid; i < nbuck; i += 256) {
        int c = lcnt[i];
        lbase[i] = c ? atomicAdd(&bucket_cursor[i], c) : 0;
        lcnt[i] = 0;
    }
    __syncthreads();
    float inv = 1.f / (float)E;
    float m0 = easum[0] * inv, m1 = easum[1] * inv;
    for (int i = base + tid; i < end; i += 256) {
        int s, d; float ex, ey;
        if (i < E) {
            s = ei[i]; d = ei[E + i];
            float2 v = ea[i]; ex = v.x; ey = v.y;
        } else {
            s = d = i - E; ex = m0; ey = m1;
        }
        int b = d >> BSH;
        int pos = lbase[b] + atomicAdd(&lcnt[b], 1);
        staged[pos] = make_float4(__int_as_float(s), ex, ey, __int_as_float(d));
    }
}

// per bucket: per-node LDS count + scan -> row_ptr; exact CSR placement
__global__ __launch_bounds__(256) void phaseB_kernel(const float4* __restrict__ staged,
                                                     const int* __restrict__ bucket_base,
                                                     int* __restrict__ row_ptr,
                                                     float4* __restrict__ recs, int N) {
    __shared__ int cnt128[128];
    __shared__ int offs[128];
    int b = blockIdx.x;
    int n0 = b << BSH;
    int tid = threadIdx.x;
    if (tid < 128) cnt128[tid] = 0;
    __syncthreads();
    int begs = bucket_base[b];
    int ends = bucket_base[b + 1];
    for (int i = begs + tid; i < ends; i += 256) {
        int d = __float_as_int(staged[i].w);
        atomicAdd(&cnt128[d - n0], 1);
    }
    __syncthreads();
    if (tid < 128) offs[tid] = cnt128[tid];
    __syncthreads();
    for (int st = 1; st < 128; st <<= 1) {
        int v = 0;
        if (tid < 128) {
            v = offs[tid];
            if (tid >= st) v += offs[tid - st];
        }
        __syncthreads();
        if (tid < 128) offs[tid] = v;
        __syncthreads();
    }
    if (tid < 128) {
        int excl = begs + offs[tid] - cnt128[tid];
        int node = n0 + tid;
        if (node < N) row_ptr[node] = excl;
        offs[tid] = excl;
    }
    __syncthreads();
    for (int i = begs + tid; i < ends; i += 256) {
        float4 r = staged[i];
        int d = __float_as_int(r.w);
        int pos = atomicAdd(&offs[d - n0], 1);
        recs[pos] = r;
    }
}

// ---- agg0: fused attention+aggregation, layer 0 (z from x, 8B gathers) ------
// 8 edges per pass; transposed reduce; one exp per pass.
__global__ __launch_bounds__(256) void agg0_kernel(
    const float2* __restrict__ x, const float* __restrict__ W0,
    const float* __restrict__ b0, const int* __restrict__ row_ptr,
    const float4* __restrict__ recs,
    const float* __restrict__ We, const float* __restrict__ att,
    const float* __restrict__ bias, float* __restrict__ hout, int N) {
    int gtid = blockIdx.x * blockDim.x + threadIdx.x;
    int n = gtid >> 6;
    if (n >= N) return;
    n = __builtin_amdgcn_readfirstlane(n);
    int lane = threadIdx.x & 63;
    bool c0 = lane & 1, c1 = lane & 2, c2 = lane & 4;

    float W0a = W0[lane], W0b = W0[64 + lane], b0c = b0[lane];
    float We0 = We[lane], We1 = We[64 + lane];
    float attj = att[lane];
    float2 xn = x[n];
    float zn = fmaf(xn.x, W0a, fmaf(xn.y, W0b, b0c));

    int beg = row_ptr[n], end = row_ptr[n + 1];
    float ll[4] = {0.f, 0.f, 0.f, 0.f};
    float aa[4] = {0.f, 0.f, 0.f, 0.f};
    for (int i = beg; i < end; i += 8) {
        float p[8], zs[8], ry[8], rz[8];
#pragma unroll
        for (int k = 0; k < 8; ++k) {
            int idx = i + k; if (idx > end - 1) idx = end - 1;
            float4 r = recs[idx];
            int s = __builtin_amdgcn_readfirstlane(__float_as_int(r.x));
            float2 xs = x[s];
            zs[k] = fmaf(xs.x, W0a, fmaf(xs.y, W0b, b0c));
            ry[k] = r.y; rz[k] = r.z;
        }
#pragma unroll
        for (int k = 0; k < 8; ++k) {
            float sj = zn + zs[k] + fmaf(ry[k], We0, rz[k] * We1);
            sj = fmaxf(sj, 0.2f * sj);           // leaky_relu(0.2)
            float t = sj * attj;
            t = dpp_add<0xB1>(t);                // xor1
            t = dpp_add<0x4E>(t);                // xor2
            t = dpp_add<0x141>(t);               // close 8-lane group
            p[k] = t;
        }
        // transpose: v = p[lane&7]
        float t0 = c0 ? p[1] : p[0];
        float t1 = c0 ? p[3] : p[2];
        float t2 = c0 ? p[5] : p[4];
        float t3 = c0 ? p[7] : p[6];
        float u0 = c1 ? t1 : t0;
        float u1 = c1 ? t3 : t2;
        float v  = c2 ? u1 : u0;
        v = dpp_add<0x128>(v);                   // xor8 (row_ror:8)
        v += swz<0x401F>(v);                     // xor16 (within head half)
        float wall = __expf(fminf(v, 60.f));     // ONE exp for 8 edges x 2 heads
        // redistribute: src = (lane&0x18) | k
        float wk[8];
        wk[0] = swz<0x018>(wall); wk[1] = swz<0x038>(wall);
        wk[2] = swz<0x058>(wall); wk[3] = swz<0x078>(wall);
        wk[4] = swz<0x098>(wall); wk[5] = swz<0x0B8>(wall);
        wk[6] = swz<0x0D8>(wall); wk[7] = swz<0x0F8>(wall);
#pragma unroll
        for (int k = 0; k < 8; ++k) {
            float w = (i + k < end) ? wk[k] : 0.f;   // mask clamped tail
            ll[k & 3] += w;
            aa[k & 3] = fmaf(w, zs[k], aa[k & 3]);
        }
    }
    float l = (ll[0] + ll[1]) + (ll[2] + ll[3]);
    float a = (aa[0] + aa[1]) + (aa[2] + aa[3]);
    float v = a / (l + 1e-16f) + bias[lane];
    v = (v > 0.f) ? v : expm1f(v);               // ELU
    hout[(size_t)n * 64 + lane] = v;
}

// ---- agg1: fused attention+aggregation, layer 1 (z gathered, 256B rows) -----
__global__ __launch_bounds__(256) void agg1_kernel(
    const float* __restrict__ z, const int* __restrict__ row_ptr,
    const float4* __restrict__ recs,
    const float* __restrict__ We, const float* __restrict__ att,
    const float* __restrict__ bias, float* __restrict__ hout, int N) {
    int gtid = blockIdx.x * blockDim.x + threadIdx.x;
    int n = gtid >> 6;
    if (n >= N) return;
    n = __builtin_amdgcn_readfirstlane(n);
    int lane = threadIdx.x & 63;
    bool c0 = lane & 1, c1 = lane & 2, c2 = lane & 4;

    float We0 = We[lane], We1 = We[64 + lane];
    float attj = att[lane];
    float zn = z[(size_t)n * 64 + lane];

    int beg = row_ptr[n], end = row_ptr[n + 1];
    float ll[4] = {0.f, 0.f, 0.f, 0.f};
    float aa[4] = {0.f, 0.f, 0.f, 0.f};
    for (int i = beg; i < end; i += 8) {
        float p[8], zs[8], ry[8], rz[8];
        int sidx[8];
#pragma unroll
        for (int k = 0; k < 8; ++k) {
            int idx = i + k; if (idx > end - 1) idx = end - 1;
            float4 r = recs[idx];
            sidx[k] = __builtin_amdgcn_readfirstlane(__float_as_int(r.x));
            ry[k] = r.y; rz[k] = r.z;
        }
#pragma unroll
        for (int k = 0; k < 8; ++k) zs[k] = z[(size_t)sidx[k] * 64 + lane];
#pragma unroll
        for (int k = 0; k < 8; ++k) {
            float sj = zn + zs[k] + fmaf(ry[k], We0, rz[k] * We1);
            sj = fmaxf(sj, 0.2f * sj);
            float t = sj * attj;
            t = dpp_add<0xB1>(t);
            t = dpp_add<0x4E>(t);
            t = dpp_add<0x141>(t);
            p[k] = t;
        }
        float t0 = c0 ? p[1] : p[0];
        float t1 = c0 ? p[3] : p[2];
        float t2 = c0 ? p[5] : p[4];
        float t3 = c0 ? p[7] : p[6];
        float u0 = c1 ? t1 : t0;
        float u1 = c1 ? t3 : t2;
        float v  = c2 ? u1 : u0;
        v = dpp_add<0x128>(v);
        v += swz<0x401F>(v);
        float wall = __expf(fminf(v, 60.f));
        float wk[8];
        wk[0] = swz<0x018>(wall); wk[1] = swz<0x038>(wall);
        wk[2] = swz<0x058>(wall); wk[3] = swz<0x078>(wall);
        wk[4] = swz<0x098>(wall); wk[5] = swz<0x0B8>(wall);
        wk[6] = swz<0x0D8>(wall); wk[7] = swz<0x0F8>(wall);
#pragma unroll
        for (int k = 0; k < 8; ++k) {
            float w = (i + k < end) ? wk[k] : 0.f;
            ll[k & 3] += w;
            aa[k & 3] = fmaf(w, zs[k], aa[k & 3]);
        }
    }
    float l = (ll[0] + ll[1]) + (ll[2] + ll[3]);
    float a = (aa[0] + aa[1]) + (aa[2] + aa[3]);
    float v = a / (l + 1e-16f) + bias[lane];
    v = (v > 0.f) ? v : expm1f(v);
    hout[(size_t)n * 64 + lane] = v;
}

// ---- out[N x 64] = h[N x 64] @ B[64 x 64] (+ bias), split-bf16 MFMA ---------
// optional gvec fold: block 0 threads 0-31 also compute the goal vector.
__global__ __launch_bounds__(256) void mfma_gemm64(const float* __restrict__ h,
                                                   const short* __restrict__ Bf,
                                                   const float* __restrict__ bias,
                                                   float* __restrict__ out, int N,
                                                   const float* __restrict__ Wm1,
                                                   const float* __restrict__ bm1,
                                                   const int* __restrict__ dest,
                                                   float* __restrict__ gv) {
    int wave = threadIdx.x >> 6;
    int lane = threadIdx.x & 63;
    int n0 = blockIdx.x * 64 + wave * 16;
    if (n0 < N) {
        int m = lane & 15, quad = lane >> 4;
        int arow = n0 + m;
        if (arow > N - 1) arow = N - 1;
        f32x4 acc[4] = {{0.f, 0.f, 0.f, 0.f}, {0.f, 0.f, 0.f, 0.f},
                        {0.f, 0.f, 0.f, 0.f}, {0.f, 0.f, 0.f, 0.f}};
#pragma unroll
        for (int s = 0; s < 2; ++s) {
            const float* ap = h + (size_t)arow * 64 + s * 32 + quad * 8;
            float4 a0 = *(const float4*)ap;
            float4 a1 = *(const float4*)(ap + 4);
            short8 ahi, alo;
            short2 t;
            t = bsplit(a0.x); ahi[0] = t.x; alo[0] = t.y;
            t = bsplit(a0.y); ahi[1] = t.x; alo[1] = t.y;
            t = bsplit(a0.z); ahi[2] = t.x; alo[2] = t.y;
            t = bsplit(a0.w); ahi[3] = t.x; alo[3] = t.y;
            t = bsplit(a1.x); ahi[4] = t.x; alo[4] = t.y;
            t = bsplit(a1.y); ahi[5] = t.x; alo[5] = t.y;
            t = bsplit(a1.z); ahi[6] = t.x; alo[6] = t.y;
            t = bsplit(a1.w); ahi[7] = t.x; alo[7] = t.y;
#pragma unroll
            for (int nt = 0; nt < 4; ++nt) {
                const short* bp = Bf + ((s * 4 + nt) * 2) * 512 + lane * 8;
                short8 bhi = *(const short8*)bp;
                short8 blo = *(const short8*)(bp + 512);
                acc[nt] = __builtin_amdgcn_mfma_f32_16x16x32_bf16(ahi, bhi, acc[nt], 0, 0, 0);
                acc[nt] = __builtin_amdgcn_mfma_f32_16x16x32_bf16(ahi, blo, acc[nt], 0, 0, 0);
                acc[nt] = __builtin_amdgcn_mfma_f32_16x16x32_bf16(alo, bhi, acc[nt], 0, 0, 0);
            }
        }
#pragma unroll
        for (int nt = 0; nt < 4; ++nt) {
            int col = nt * 16 + m;
            float bj = bias ? bias[col] : 0.f;
#pragma unroll
            for (int r = 0; r < 4; ++r) {
                int orow = n0 + quad * 4 + r;
                if (orow < N) out[(size_t)orow * 64 + col] = acc[nt][r] + bj;
            }
        }
    }
    if (gv && blockIdx.x == 0 && threadIdx.x < 32) {
        int dd = dest[0];
        int q = threadIdx.x;
        float acc2 = bm1[q];
        for (int k = 0; k < 64; ++k)
            acc2 = fmaf(h[(size_t)dd * 64 + k], Wm1[(128 + k) * 32 + q], acc2);
        gv[q] = acc2;
    }
}

// 8 lanes per edge; hsd[n*64+0:32]=hs, hsd[n*64+32:64]=hd
__global__ __launch_bounds__(256) void edge_mlp_kernel(
    const int* __restrict__ ei, const float2* __restrict__ ea,
    const float* __restrict__ hsd, const float* __restrict__ gvec,
    const float* __restrict__ WrowA, const float* __restrict__ WrowB,
    const float* __restrict__ Wm2, const float* __restrict__ bm2,
    float* __restrict__ out, int E) {
    int tid = blockIdx.x * blockDim.x + threadIdx.x;
    int e = tid >> 3;
    int j = tid & 7;
    if (e >= E) return;
    int s = ei[e], d = ei[E + e];
    float2 eav = ea[e];
    float4 a = *(const float4*)(hsd + (size_t)s * 64 + j * 4);
    float4 bv = *(const float4*)(hsd + (size_t)d * 64 + 32 + j * 4);
    float4 g = *(const float4*)(gvec + j * 4);
    float4 wa = *(const float4*)(WrowA + j * 4);
    float4 wb = *(const float4*)(WrowB + j * 4);
    float4 w2 = *(const float4*)(Wm2 + j * 4);
    float acc = 0.f, v;
    v = fmaf(eav.x, wa.x, fmaf(eav.y, wb.x, a.x + bv.x + g.x)); v = fmaxf(v, 0.f); acc = fmaf(v, w2.x, acc);
    v = fmaf(eav.x, wa.y, fmaf(eav.y, wb.y, a.y + bv.y + g.y)); v = fmaxf(v, 0.f); acc = fmaf(v, w2.y, acc);
    v = fmaf(eav.x, wa.z, fmaf(eav.y, wb.z, a.z + bv.z + g.z)); v = fmaxf(v, 0.f); acc = fmaf(v, w2.z, acc);
    v = fmaf(eav.x, wa.w, fmaf(eav.y, wb.w, a.w + bv.w + g.w)); v = fmaxf(v, 0.f); acc = fmaf(v, w2.w, acc);
    acc = dpp_add<0xB1>(acc);
    acc = dpp_add<0x4E>(acc);
    acc = dpp_add<0x141>(acc);
    if (j == 0) out[e] = acc + bm2[0];
}

extern "C" void kernel_launch(void* const* d_in, const int* in_sizes, int n_in,
                              void* d_out, int out_size, void* d_ws, size_t ws_size,
                              hipStream_t stream) {
    const float* x     = (const float*)d_in[0];
    const int*   ei    = (const int*)d_in[1];
    const float* ea    = (const float*)d_in[2];
    const int*   dest  = (const int*)d_in[3];
    const float* W0    = (const float*)d_in[4];
    const float* b0    = (const float*)d_in[5];
    const float* We0   = (const float*)d_in[6];
    const float* att0  = (const float*)d_in[7];
    const float* bias0 = (const float*)d_in[8];
    const float* W1    = (const float*)d_in[9];
    const float* b1    = (const float*)d_in[10];
    const float* We1   = (const float*)d_in[11];
    const float* att1  = (const float*)d_in[12];
    const float* bias1 = (const float*)d_in[13];
    const float* Wm1   = (const float*)d_in[14];
    const float* bm1   = (const float*)d_in[15];
    const float* Wm2   = (const float*)d_in[16];
    const float* bm2   = (const float*)d_in[17];

    const int N = in_sizes[0] / 2;
    const int E = in_sizes[1] / 2;
    const int EP = E + N;
    const int nbuck = (N + 127) >> BSH;
    const int nchunk = (EP + CH - 1) / CH;

    char* ws = (char*)d_ws;
    size_t off = 0;
    auto alloc = [&](size_t bytes) -> void* {
        void* p = ws + off;
        off += bytes;
        off = (off + 255) & ~(size_t)255;
        return p;
    };
    int*    bucket_base   = (int*)alloc((size_t)(nbuck + 1) * 4);
    int*    bucket_cursor = (int*)alloc((size_t)nbuck * 4);
    int*    row_ptr       = (int*)alloc((size_t)(N + 1) * 4);
    size_t  shared_bytes  = (size_t)EP * 16 > (size_t)N * 256 ? (size_t)EP * 16
                                                              : (size_t)N * 256;
    float4* staged        = (float4*)alloc(shared_bytes);
    float4* recs          = (float4*)alloc((size_t)EP * 16);
    float*  hbuf          = (float*)alloc((size_t)N * 64 * 4);
    float*  easum         = (float*)alloc(8);
    float*  gvec          = (float*)alloc(32 * 4);
    short*  BfW1          = (short*)alloc(8192 * 2);
    short*  BfWm          = (short*)alloc(8192 * 2);
    float*  zbuf          = (float*)staged;   // staged dead before gemm writes
    float*  hsd           = zbuf;             // z1 dead after layer-1 agg

    dim3 blk(256);
    setup_kernel<<<3, 512, 0, stream>>>(W1, Wm1, BfW1, BfWm, bucket_base, easum, nbuck);
    pre_kernel<<<nchunk, blk, (size_t)nbuck * 4, stream>>>(ei, (const float2*)ea,
                                                           bucket_base, easum, E, EP, nbuck);
    bscan_kernel<<<1, blk, 0, stream>>>(bucket_base, bucket_cursor, row_ptr, N, nbuck);
    phaseA_kernel<<<nchunk, blk, (size_t)nbuck * 8, stream>>>(ei, (const float2*)ea, easum,
                                                              bucket_cursor, staged, E, EP, nbuck);
    phaseB_kernel<<<nbuck, blk, 0, stream>>>(staged, bucket_base, row_ptr, recs, N);
    agg0_kernel<<<(N * 64 + 255) / 256, blk, 0, stream>>>((const float2*)x, W0, b0,
                                                          row_ptr, recs,
                                                          We0, att0, bias0, hbuf, N);
    mfma_gemm64<<<(N + 63) / 64, blk, 0, stream>>>(hbuf, BfW1, b1, zbuf, N,
                                                   nullptr, nullptr, nullptr, nullptr);
    agg1_kernel<<<(N * 64 + 255) / 256, blk, 0, stream>>>(zbuf, row_ptr, recs,
                                                          We1, att1, bias1, hbuf, N);
    mfma_gemm64<<<(N + 63) / 64, blk, 0, stream>>>(hbuf, BfWm, (const float*)nullptr, hsd, N,
                                                   Wm1, bm1, dest, gvec);
    edge_mlp_kernel<<<((size_t)E * 8 + 255) / 256, blk, 0, stream>>>(
        ei, (const float2*)ea, hsd, gvec,
        Wm1 + 192 * 32, Wm1 + 193 * 32, Wm2, bm2, (float*)d_out, E);
}

// Round 10
// 282.115 us; speedup vs baseline: 1.2026x; 1.0107x over previous
//
#include <hip/hip_runtime.h>
#include <hip/hip_bf16.h>
#include <math.h>

// ---------------------------------------------------------------------------
// GATv2 policy net: 2x GATv2 layer (H=2, C=32, share_weights) + edge MLP.
// CSR build = bucketed counting sort (128 nodes/bucket), LDS counting.
// Layer 0 uses the rank-2 decomposition (x is 2-dim):
//   Sum w*z[src] = W0a*Sum(w*xs.x) + W0b*Sum(w*xs.y) + b0*Sum(w)
//   -> wgt0 (edge-parallel, 16 edges/wave): w0,w1 per edge -> wrec
//   -> hagg0 (wave/node, lanes=EDGES): stream wrec, 6-scalar butterfly,
//      rank-2 epilogue with lanes=channels. No serial per-edge chain.
// Layer 1: fused attention+aggregation (R7 ILP-8 form, lane=channel).
// Unnormalized softmax (clamp 60): exp cannot overflow; same math.
// Fusions: init+bfrag (setup); easum+bhist (pre); gvec inside 2nd gemm.
// ---------------------------------------------------------------------------

typedef __attribute__((ext_vector_type(8))) short short8;
typedef __attribute__((ext_vector_type(4))) float f32x4;

#define BSH 7               // 128 nodes per bucket
#define CH 4096             // edges per block in pre/phaseA

template <int IMM>
__device__ __forceinline__ float swz(float x) {
    return __int_as_float(__builtin_amdgcn_ds_swizzle(__float_as_int(x), IMM));
}

template <int CTRL>
__device__ __forceinline__ float dpp_add(float p) {
    int t = __builtin_amdgcn_update_dpp(0, __float_as_int(p), CTRL, 0xF, 0xF, true);
    return p + __int_as_float(t);
}

// sum over the 32 lanes of this head; result in all lanes.
__device__ __forceinline__ float head_reduce(float p) {
    p = dpp_add<0xB1>(p);     // xor 1
    p = dpp_add<0x4E>(p);     // xor 2
    p = dpp_add<0x141>(p);    // xor 7 (half mirror)
    p = dpp_add<0x140>(p);    // xor 15 (row mirror)
    p += swz<0x401F>(p);      // xor 16
    return p;
}

// truncating fp32 -> (hi, lo) bf16 split
__device__ __forceinline__ short2 bsplit(float x) {
    unsigned u = __float_as_uint(x);
    short hi = (short)(u >> 16);
    float hif = __uint_as_float(u & 0xFFFF0000u);
    short lo = (short)(__float_as_uint(x - hif) >> 16);
    return make_short2(hi, lo);
}

// ---- setup: blocks 0,1 = bfrag (split-bf16 B fragments); block 2 = zeroing --
__global__ __launch_bounds__(512) void setup_kernel(const float* __restrict__ W1,
                                                    const float* __restrict__ Wm1,
                                                    short* __restrict__ BfW1,
                                                    short* __restrict__ BfWm,
                                                    int* __restrict__ bucket_base,
                                                    float* __restrict__ easum, int nbuck) {
    if (blockIdx.x == 2) {
        for (int i = threadIdx.x; i <= nbuck; i += 512) bucket_base[i] = 0;
        if (threadIdx.x < 2) easum[threadIdx.x] = 0.f;
        return;
    }
    int snt = threadIdx.x >> 6;
    int lane = threadIdx.x & 63;
    int s = snt >> 2, nt = snt & 3;
    int col = nt * 16 + (lane & 15);
    short* Bf = blockIdx.x == 0 ? BfW1 : BfWm;
#pragma unroll
    for (int j = 0; j < 8; ++j) {
        int k = s * 32 + (lane >> 4) * 8 + j;
        float v;
        if (blockIdx.x == 0) {
            v = W1[k * 64 + col];
        } else {
            v = (col < 32) ? Wm1[k * 32 + col] : Wm1[(64 + k) * 32 + (col - 32)];
        }
        short2 t = bsplit(v);
        Bf[(snt * 2 + 0) * 512 + lane * 8 + j] = t.x;
        Bf[(snt * 2 + 1) * 512 + lane * 8 + j] = t.y;
    }
}

// ---- pre: easum (block-tree + 2 atomics/block) fused with bucket histogram --
__global__ __launch_bounds__(256) void pre_kernel(const int* __restrict__ ei,
                                                  const float2* __restrict__ ea,
                                                  int* __restrict__ bucket_base,
                                                  float* __restrict__ easum,
                                                  int E, int EP, int nbuck) {
    extern __shared__ int lcnt[];
    __shared__ float r0[4], r1[4];
    int tid = threadIdx.x;
    for (int i = tid; i < nbuck; i += 256) lcnt[i] = 0;
    float s0 = 0.f, s1 = 0.f;
    int estride = gridDim.x * 256;
    for (int e = blockIdx.x * 256 + tid; e < E; e += estride) {
        float2 v = ea[e];
        s0 += v.x; s1 += v.y;
    }
#pragma unroll
    for (int o = 32; o >= 1; o >>= 1) {
        s0 += __shfl_xor(s0, o);
        s1 += __shfl_xor(s1, o);
    }
    int wave = tid >> 6;
    if ((tid & 63) == 0) { r0[wave] = s0; r1[wave] = s1; }
    __syncthreads();
    int base = blockIdx.x * CH;
    int end = min(base + CH, EP);
    for (int i = base + tid; i < end; i += 256) {
        int d = (i < E) ? ei[E + i] : (i - E);
        atomicAdd(&lcnt[d >> BSH], 1);
    }
    __syncthreads();
    if (tid == 0) {
        atomicAdd(&easum[0], r0[0] + r0[1] + r0[2] + r0[3]);
        atomicAdd(&easum[1], r1[0] + r1[1] + r1[2] + r1[3]);
    }
    for (int i = tid; i < nbuck; i += 256) {
        int c = lcnt[i];
        if (c) atomicAdd(&bucket_base[i], c);
    }
}

// single-block exclusive scan of bucket counts
__global__ __launch_bounds__(256) void bscan_kernel(int* __restrict__ bucket_base,
                                                    int* __restrict__ bucket_cursor,
                                                    int* __restrict__ row_ptr,
                                                    int N, int nbuck) {
    __shared__ int sm[256];
    int tid = threadIdx.x;
    int K = (nbuck + 255) / 256;
    int b0 = tid * K;
    int local = 0;
    for (int k = 0; k < K; ++k) {
        int b = b0 + k;
        if (b < nbuck) local += bucket_base[b];
    }
    sm[tid] = local;
    __syncthreads();
    for (int st = 1; st < 256; st <<= 1) {
        int v = sm[tid];
        int a = (tid >= st) ? sm[tid - st] : 0;
        __syncthreads();
        sm[tid] = v + a;
        __syncthreads();
    }
    int run = (tid == 0) ? 0 : sm[tid - 1];
    for (int k = 0; k < K; ++k) {
        int b = b0 + k;
        if (b < nbuck) {
            int c = bucket_base[b];
            bucket_base[b] = run;
            bucket_cursor[b] = run;
            run += c;
        }
    }
    if (tid == 255) {
        bucket_base[nbuck] = sm[255];
        row_ptr[N] = sm[255];
    }
}

// partition edges into bucket-contiguous staged[]; records {src, eax, eay, dst}
__global__ __launch_bounds__(256) void phaseA_kernel(const int* __restrict__ ei,
                                                     const float2* __restrict__ ea,
                                                     const float* __restrict__ easum,
                                                     int* __restrict__ bucket_cursor,
                                                     float4* __restrict__ staged,
                                                     int E, int EP, int nbuck) {
    extern __shared__ int sm[];          // lcnt[nbuck] then lbase[nbuck]
    int* lcnt = sm;
    int* lbase = sm + nbuck;
    int tid = threadIdx.x;
    for (int i = tid; i < nbuck; i += 256) lcnt[i] = 0;
    __syncthreads();
    int base = blockIdx.x * CH;
    int end = min(base + CH, EP);
    for (int i = base + tid; i < end; i += 256) {
        int d = (i < E) ? ei[E + i] : (i - E);
        atomicAdd(&lcnt[d >> BSH], 1);
    }
    __syncthreads();
    for (int i = tid; i < nbuck; i += 256) {
        int c = lcnt[i];
        lbase[i] = c ? atomicAdd(&bucket_cursor[i], c) : 0;
        lcnt[i] = 0;
    }
    __syncthreads();
    float inv = 1.f / (float)E;
    float m0 = easum[0] * inv, m1 = easum[1] * inv;
    for (int i = base + tid; i < end; i += 256) {
        int s, d; float ex, ey;
        if (i < E) {
            s = ei[i]; d = ei[E + i];
            float2 v = ea[i]; ex = v.x; ey = v.y;
        } else {
            s = d = i - E; ex = m0; ey = m1;
        }
        int b = d >> BSH;
        int pos = lbase[b] + atomicAdd(&lcnt[b], 1);
        staged[pos] = make_float4(__int_as_float(s), ex, ey, __int_as_float(d));
    }
}

// per bucket: per-node LDS count + scan -> row_ptr; exact CSR placement
__global__ __launch_bounds__(256) void phaseB_kernel(const float4* __restrict__ staged,
                                                     const int* __restrict__ bucket_base,
                                                     int* __restrict__ row_ptr,
                                                     float4* __restrict__ recs, int N) {
    __shared__ int cnt128[128];
    __shared__ int offs[128];
    int b = blockIdx.x;
    int n0 = b << BSH;
    int tid = threadIdx.x;
    if (tid < 128) cnt128[tid] = 0;
    __syncthreads();
    int begs = bucket_base[b];
    int ends = bucket_base[b + 1];
    for (int i = begs + tid; i < ends; i += 256) {
        int d = __float_as_int(staged[i].w);
        atomicAdd(&cnt128[d - n0], 1);
    }
    __syncthreads();
    if (tid < 128) offs[tid] = cnt128[tid];
    __syncthreads();
    for (int st = 1; st < 128; st <<= 1) {
        int v = 0;
        if (tid < 128) {
            v = offs[tid];
            if (tid >= st) v += offs[tid - st];
        }
        __syncthreads();
        if (tid < 128) offs[tid] = v;
        __syncthreads();
    }
    if (tid < 128) {
        int excl = begs + offs[tid] - cnt128[tid];
        int node = n0 + tid;
        if (node < N) row_ptr[node] = excl;
        offs[tid] = excl;
    }
    __syncthreads();
    for (int i = begs + tid; i < ends; i += 256) {
        float4 r = staged[i];
        int d = __float_as_int(r.w);
        int pos = atomicAdd(&offs[d - n0], 1);
        recs[pos] = r;
    }
}

// ---- wgt0: edge-parallel layer-0 attention weights --------------------------
// 16 edges per wave; lane(m=lane&15, quad) covers channels quad*8..+7 of each
// head. z recomputed from x (2 fma). Writes wrec = {w0, w1, xs.x, xs.y}.
__global__ __launch_bounds__(256) void wgt0_kernel(const float2* __restrict__ x,
                                                   const float* __restrict__ W0,
                                                   const float* __restrict__ b0,
                                                   const float4* __restrict__ recs,
                                                   const float* __restrict__ We,
                                                   const float* __restrict__ att,
                                                   float4* __restrict__ wrec, int EP) {
    int lane = threadIdx.x & 63;
    int m = lane & 15, quad = lane >> 4;
    int c0 = quad * 8, c1 = 32 + c0;
    float w0a[8], w1a[8], ata[8], w0b[8], w1b[8], atb[8];
    float Wxa[8], Wya[8], bca[8], Wxb[8], Wyb[8], bcb[8];
#pragma unroll
    for (int j = 0; j < 8; ++j) {
        w0a[j] = We[c0 + j];  w1a[j] = We[64 + c0 + j];  ata[j] = att[c0 + j];
        w0b[j] = We[c1 + j];  w1b[j] = We[64 + c1 + j];  atb[j] = att[c1 + j];
        Wxa[j] = W0[c0 + j];  Wya[j] = W0[64 + c0 + j];  bca[j] = b0[c0 + j];
        Wxb[j] = W0[c1 + j];  Wyb[j] = W0[64 + c1 + j];  bcb[j] = b0[c1 + j];
    }
    int ntiles = (EP + 15) >> 4;
    int wid = (blockIdx.x * blockDim.x + threadIdx.x) >> 6;
    int nw = (gridDim.x * blockDim.x) >> 6;
    for (int t = wid; t < ntiles; t += nw) {
        int e = t * 16 + m;
        int ec = e < EP ? e : EP - 1;
        float4 r = recs[ec];
        int s = __float_as_int(r.x);
        int d = __float_as_int(r.w);
        float2 xs = x[s];
        float2 xd = x[d];
        float P0 = 0.f, P1 = 0.f;
#pragma unroll
        for (int j = 0; j < 8; ++j) {
            float zs = fmaf(xs.x, Wxa[j], fmaf(xs.y, Wya[j], bca[j]));
            float zd = fmaf(xd.x, Wxa[j], fmaf(xd.y, Wya[j], bca[j]));
            float t0 = zd + zs + fmaf(r.y, w0a[j], r.z * w1a[j]);
            t0 = fmaxf(t0, 0.2f * t0);
            P0 = fmaf(t0, ata[j], P0);
            float zs1 = fmaf(xs.x, Wxb[j], fmaf(xs.y, Wyb[j], bcb[j]));
            float zd1 = fmaf(xd.x, Wxb[j], fmaf(xd.y, Wyb[j], bcb[j]));
            float t1 = zd1 + zs1 + fmaf(r.y, w0b[j], r.z * w1b[j]);
            t1 = fmaxf(t1, 0.2f * t1);
            P1 = fmaf(t1, atb[j], P1);
        }
        P0 += swz<0x401F>(P0);             // quad pair (xor 16)
        P1 += swz<0x401F>(P1);
        P0 += __shfl_xor(P0, 32);          // cross-half (xor 32)
        P1 += __shfl_xor(P1, 32);
        float w0 = __expf(fminf(P0, 60.f));
        float w1 = __expf(fminf(P1, 60.f));
        if (lane < 16 && e < EP) wrec[e] = make_float4(w0, w1, xs.x, xs.y);
    }
}

// ---- hagg0: wave/node, lanes=EDGES; stream wrec; 6-scalar butterfly ---------
// rank-2 epilogue: h_j = (W0a_j*Sx + W0b_j*Sy + b0_j*l)/l + bias_j, ELU.
__global__ __launch_bounds__(256) void hagg0_kernel(const float4* __restrict__ wrec,
                                                    const int* __restrict__ row_ptr,
                                                    const float* __restrict__ W0,
                                                    const float* __restrict__ b0,
                                                    const float* __restrict__ bias,
                                                    float* __restrict__ hout, int N) {
    int gtid = blockIdx.x * blockDim.x + threadIdx.x;
    int n = gtid >> 6;
    if (n >= N) return;
    n = __builtin_amdgcn_readfirstlane(n);
    int lane = threadIdx.x & 63;
    int beg = row_ptr[n], end = row_ptr[n + 1];
    float a0 = 0.f, a1 = 0.f, a2 = 0.f, c0 = 0.f, c1 = 0.f, c2 = 0.f;
    for (int i = beg + lane; i < end; i += 64) {
        float4 r = wrec[i];
        a0 += r.x; a1 = fmaf(r.x, r.z, a1); a2 = fmaf(r.x, r.w, a2);
        c0 += r.y; c1 = fmaf(r.y, r.z, c1); c2 = fmaf(r.y, r.w, c2);
    }
#pragma unroll
    for (int o = 32; o >= 1; o >>= 1) {
        a0 += __shfl_xor(a0, o); a1 += __shfl_xor(a1, o); a2 += __shfl_xor(a2, o);
        c0 += __shfl_xor(c0, o); c1 += __shfl_xor(c1, o); c2 += __shfl_xor(c2, o);
    }
    int head = lane >> 5;
    float l  = head ? c0 : a0;
    float Sx = head ? c1 : a1;
    float Sy = head ? c2 : a2;
    float num = fmaf(W0[lane], Sx, fmaf(W0[64 + lane], Sy, b0[lane] * l));
    float v = num / (l + 1e-16f) + bias[lane];
    v = (v > 0.f) ? v : expm1f(v);       // ELU
    hout[(size_t)n * 64 + lane] = v;
}

// ---- agg1: fused attention+aggregation, layer 1 (R7 ILP-8, lane=channel) ----
__global__ __launch_bounds__(256) void agg1_kernel(
    const float* __restrict__ z, const int* __restrict__ row_ptr,
    const float4* __restrict__ recs,
    const float* __restrict__ We, const float* __restrict__ att,
    const float* __restrict__ bias, float* __restrict__ hout, int N) {
    int gtid = blockIdx.x * blockDim.x + threadIdx.x;
    int n = gtid >> 6;
    if (n >= N) return;
    n = __builtin_amdgcn_readfirstlane(n);
    int lane = threadIdx.x & 63;

    float We0 = We[lane], We1 = We[64 + lane];
    float attj = att[lane];
    float zn = z[(size_t)n * 64 + lane];

    int beg = row_ptr[n], end = row_ptr[n + 1];
    float ll[4] = {0.f, 0.f, 0.f, 0.f};
    float aa[4] = {0.f, 0.f, 0.f, 0.f};
    int i = beg;
    for (; i + 8 <= end; i += 8) {
        float w[8], zs[8];
#pragma unroll
        for (int k = 0; k < 8; ++k) {
            float4 r = recs[i + k];
            int s = __builtin_amdgcn_readfirstlane(__float_as_int(r.x));
            float zv = z[(size_t)s * 64 + lane];
            float sj = zn + zv + fmaf(r.y, We0, r.z * We1);
            sj = fmaxf(sj, 0.2f * sj);
            float alpha = head_reduce(sj * attj);
            w[k] = __expf(fminf(alpha, 60.f));
            zs[k] = zv;
        }
#pragma unroll
        for (int k = 0; k < 8; ++k) {
            ll[k & 3] += w[k];
            aa[k & 3] = fmaf(w[k], zs[k], aa[k & 3]);
        }
    }
    for (; i < end; ++i) {
        float4 r = recs[i];
        int s = __builtin_amdgcn_readfirstlane(__float_as_int(r.x));
        float zv = z[(size_t)s * 64 + lane];
        float sj = zn + zv + fmaf(r.y, We0, r.z * We1);
        sj = fmaxf(sj, 0.2f * sj);
        float alpha = head_reduce(sj * attj);
        float w = __expf(fminf(alpha, 60.f));
        ll[0] += w;
        aa[0] = fmaf(w, zv, aa[0]);
    }
    float l = (ll[0] + ll[1]) + (ll[2] + ll[3]);
    float a = (aa[0] + aa[1]) + (aa[2] + aa[3]);
    float v = a / (l + 1e-16f) + bias[lane];
    v = (v > 0.f) ? v : expm1f(v);
    hout[(size_t)n * 64 + lane] = v;
}

// ---- out[N x 64] = h[N x 64] @ B[64 x 64] (+ bias), split-bf16 MFMA ---------
// optional gvec fold: block 0 threads 0-31 also compute the goal vector.
__global__ __launch_bounds__(256) void mfma_gemm64(const float* __restrict__ h,
                                                   const short* __restrict__ Bf,
                                                   const float* __restrict__ bias,
                                                   float* __restrict__ out, int N,
                                                   const float* __restrict__ Wm1,
                                                   const float* __restrict__ bm1,
                                                   const int* __restrict__ dest,
                                                   float* __restrict__ gv) {
    int wave = threadIdx.x >> 6;
    int lane = threadIdx.x & 63;
    int n0 = blockIdx.x * 64 + wave * 16;
    if (n0 < N) {
        int m = lane & 15, quad = lane >> 4;
        int arow = n0 + m;
        if (arow > N - 1) arow = N - 1;
        f32x4 acc[4] = {{0.f, 0.f, 0.f, 0.f}, {0.f, 0.f, 0.f, 0.f},
                        {0.f, 0.f, 0.f, 0.f}, {0.f, 0.f, 0.f, 0.f}};
#pragma unroll
        for (int s = 0; s < 2; ++s) {
            const float* ap = h + (size_t)arow * 64 + s * 32 + quad * 8;
            float4 a0 = *(const float4*)ap;
            float4 a1 = *(const float4*)(ap + 4);
            short8 ahi, alo;
            short2 t;
            t = bsplit(a0.x); ahi[0] = t.x; alo[0] = t.y;
            t = bsplit(a0.y); ahi[1] = t.x; alo[1] = t.y;
            t = bsplit(a0.z); ahi[2] = t.x; alo[2] = t.y;
            t = bsplit(a0.w); ahi[3] = t.x; alo[3] = t.y;
            t = bsplit(a1.x); ahi[4] = t.x; alo[4] = t.y;
            t = bsplit(a1.y); ahi[5] = t.x; alo[5] = t.y;
            t = bsplit(a1.z); ahi[6] = t.x; alo[6] = t.y;
            t = bsplit(a1.w); ahi[7] = t.x; alo[7] = t.y;
#pragma unroll
            for (int nt = 0; nt < 4; ++nt) {
                const short* bp = Bf + ((s * 4 + nt) * 2) * 512 + lane * 8;
                short8 bhi = *(const short8*)bp;
                short8 blo = *(const short8*)(bp + 512);
                acc[nt] = __builtin_amdgcn_mfma_f32_16x16x32_bf16(ahi, bhi, acc[nt], 0, 0, 0);
                acc[nt] = __builtin_amdgcn_mfma_f32_16x16x32_bf16(ahi, blo, acc[nt], 0, 0, 0);
                acc[nt] = __builtin_amdgcn_mfma_f32_16x16x32_bf16(alo, bhi, acc[nt], 0, 0, 0);
            }
        }
#pragma unroll
        for (int nt = 0; nt < 4; ++nt) {
            int col = nt * 16 + m;
            float bj = bias ? bias[col] : 0.f;
#pragma unroll
            for (int r = 0; r < 4; ++r) {
                int orow = n0 + quad * 4 + r;
                if (orow < N) out[(size_t)orow * 64 + col] = acc[nt][r] + bj;
            }
        }
    }
    if (gv && blockIdx.x == 0 && threadIdx.x < 32) {
        int dd = dest[0];
        int q = threadIdx.x;
        float acc2 = bm1[q];
        for (int k = 0; k < 64; ++k)
            acc2 = fmaf(h[(size_t)dd * 64 + k], Wm1[(128 + k) * 32 + q], acc2);
        gv[q] = acc2;
    }
}

// 8 lanes per edge; hsd[n*64+0:32]=hs, hsd[n*64+32:64]=hd
__global__ __launch_bounds__(256) void edge_mlp_kernel(
    const int* __restrict__ ei, const float2* __restrict__ ea,
    const float* __restrict__ hsd, const float* __restrict__ gvec,
    const float* __restrict__ WrowA, const float* __restrict__ WrowB,
    const float* __restrict__ Wm2, const float* __restrict__ bm2,
    float* __restrict__ out, int E) {
    int tid = blockIdx.x * blockDim.x + threadIdx.x;
    int e = tid >> 3;
    int j = tid & 7;
    if (e >= E) return;
    int s = ei[e], d = ei[E + e];
    float2 eav = ea[e];
    float4 a = *(const float4*)(hsd + (size_t)s * 64 + j * 4);
    float4 bv = *(const float4*)(hsd + (size_t)d * 64 + 32 + j * 4);
    float4 g = *(const float4*)(gvec + j * 4);
    float4 wa = *(const float4*)(WrowA + j * 4);
    float4 wb = *(const float4*)(WrowB + j * 4);
    float4 w2 = *(const float4*)(Wm2 + j * 4);
    float acc = 0.f, v;
    v = fmaf(eav.x, wa.x, fmaf(eav.y, wb.x, a.x + bv.x + g.x)); v = fmaxf(v, 0.f); acc = fmaf(v, w2.x, acc);
    v = fmaf(eav.x, wa.y, fmaf(eav.y, wb.y, a.y + bv.y + g.y)); v = fmaxf(v, 0.f); acc = fmaf(v, w2.y, acc);
    v = fmaf(eav.x, wa.z, fmaf(eav.y, wb.z, a.z + bv.z + g.z)); v = fmaxf(v, 0.f); acc = fmaf(v, w2.z, acc);
    v = fmaf(eav.x, wa.w, fmaf(eav.y, wb.w, a.w + bv.w + g.w)); v = fmaxf(v, 0.f); acc = fmaf(v, w2.w, acc);
    acc = dpp_add<0xB1>(acc);
    acc = dpp_add<0x4E>(acc);
    acc = dpp_add<0x141>(acc);
    if (j == 0) out[e] = acc + bm2[0];
}

extern "C" void kernel_launch(void* const* d_in, const int* in_sizes, int n_in,
                              void* d_out, int out_size, void* d_ws, size_t ws_size,
                              hipStream_t stream) {
    const float* x     = (const float*)d_in[0];
    const int*   ei    = (const int*)d_in[1];
    const float* ea    = (const float*)d_in[2];
    const int*   dest  = (const int*)d_in[3];
    const float* W0    = (const float*)d_in[4];
    const float* b0    = (const float*)d_in[5];
    const float* We0   = (const float*)d_in[6];
    const float* att0  = (const float*)d_in[7];
    const float* bias0 = (const float*)d_in[8];
    const float* W1    = (const float*)d_in[9];
    const float* b1    = (const float*)d_in[10];
    const float* We1   = (const float*)d_in[11];
    const float* att1  = (const float*)d_in[12];
    const float* bias1 = (const float*)d_in[13];
    const float* Wm1   = (const float*)d_in[14];
    const float* bm1   = (const float*)d_in[15];
    const float* Wm2   = (const float*)d_in[16];
    const float* bm2   = (const float*)d_in[17];

    const int N = in_sizes[0] / 2;
    const int E = in_sizes[1] / 2;
    const int EP = E + N;
    const int nbuck = (N + 127) >> BSH;
    const int nchunk = (EP + CH - 1) / CH;

    char* ws = (char*)d_ws;
    size_t off = 0;
    auto alloc = [&](size_t bytes) -> void* {
        void* p = ws + off;
        off += bytes;
        off = (off + 255) & ~(size_t)255;
        return p;
    };
    int*    bucket_base   = (int*)alloc((size_t)(nbuck + 1) * 4);
    int*    bucket_cursor = (int*)alloc((size_t)nbuck * 4);
    int*    row_ptr       = (int*)alloc((size_t)(N + 1) * 4);
    size_t  shared_bytes  = (size_t)EP * 16 > (size_t)N * 256 ? (size_t)EP * 16
                                                              : (size_t)N * 256;
    float4* staged        = (float4*)alloc(shared_bytes);
    float4* recs          = (float4*)alloc((size_t)EP * 16);
    float4* wrec          = (float4*)alloc((size_t)EP * 16);
    float*  hbuf          = (float*)alloc((size_t)N * 64 * 4);
    float*  easum         = (float*)alloc(8);
    float*  gvec          = (float*)alloc(32 * 4);
    short*  BfW1          = (short*)alloc(8192 * 2);
    short*  BfWm          = (short*)alloc(8192 * 2);
    float*  zbuf          = (float*)staged;   // staged dead before gemm writes
    float*  hsd           = zbuf;             // z1 dead after layer-1 agg

    dim3 blk(256);
    setup_kernel<<<3, 512, 0, stream>>>(W1, Wm1, BfW1, BfWm, bucket_base, easum, nbuck);
    pre_kernel<<<nchunk, blk, (size_t)nbuck * 4, stream>>>(ei, (const float2*)ea,
                                                           bucket_base, easum, E, EP, nbuck);
    bscan_kernel<<<1, blk, 0, stream>>>(bucket_base, bucket_cursor, row_ptr, N, nbuck);
    phaseA_kernel<<<nchunk, blk, (size_t)nbuck * 8, stream>>>(ei, (const float2*)ea, easum,
                                                              bucket_cursor, staged, E, EP, nbuck);
    phaseB_kernel<<<nbuck, blk, 0, stream>>>(staged, bucket_base, row_ptr, recs, N);
    wgt0_kernel<<<2048, blk, 0, stream>>>((const float2*)x, W0, b0, recs, We0, att0, wrec, EP);
    hagg0_kernel<<<(N * 64 + 255) / 256, blk, 0, stream>>>(wrec, row_ptr, W0, b0,
                                                           bias0, hbuf, N);
    mfma_gemm64<<<(N + 63) / 64, blk, 0, stream>>>(hbuf, BfW1, b1, zbuf, N,
                                                   nullptr, nullptr, nullptr, nullptr);
    agg1_kernel<<<(N * 64 + 255) / 256, blk, 0, stream>>>(zbuf, row_ptr, recs,
                                                          We1, att1, bias1, hbuf, N);
    mfma_gemm64<<<(N + 63) / 64, blk, 0, stream>>>(hbuf, BfWm, (const float*)nullptr, hsd, N,
                                                   Wm1, bm1, dest, gvec);
    edge_mlp_kernel<<<((size_t)E * 8 + 255) / 256, blk, 0, stream>>>(
        ei, (const float2*)ea, hsd, gvec,
        Wm1 + 192 * 32, Wm1 + 193 * 32, Wm2, bm2, (float*)d_out, E);
}

// Round 11
// 274.076 us; speedup vs baseline: 1.2379x; 1.0293x over previous
//
#include <hip/hip_runtime.h>
#include <hip/hip_bf16.h>
#include <hip/hip_fp16.h>
#include <math.h>

// ---------------------------------------------------------------------------
// GATv2 policy net: 2x GATv2 layer (H=2, C=32, share_weights) + edge MLP.
// CSR build = bucketed counting sort (128 nodes/bucket), LDS counting.
// Layer 0: rank-2 decomposition (x is 2-dim):
//   wgt0 (edge-parallel) -> wrec{w0,w1,xs.x,xs.y}; hagg0 (lanes=edges,
//   6-scalar butterfly) + rank-2 epilogue. No serial per-edge chain.
// Layer 1: fused attention+aggregation (ILP-8, lane=channel); z1 stored FP16
//   (halves the XCD-replicated random-gather traffic, the structural floor).
// hsd (edge-MLP node halves) also FP16 for the same reason.
// Unnormalized softmax (clamp 60): exp cannot overflow; same math.
// Fusions: init+bfrag (setup); easum+bhist (pre); gvec inside 2nd gemm.
// ---------------------------------------------------------------------------

typedef __attribute__((ext_vector_type(8))) short short8;
typedef __attribute__((ext_vector_type(4))) float f32x4;

#define BSH 7               // 128 nodes per bucket
#define CH 4096             // edges per block in pre/phaseA

template <int IMM>
__device__ __forceinline__ float swz(float x) {
    return __int_as_float(__builtin_amdgcn_ds_swizzle(__float_as_int(x), IMM));
}

template <int CTRL>
__device__ __forceinline__ float dpp_add(float p) {
    int t = __builtin_amdgcn_update_dpp(0, __float_as_int(p), CTRL, 0xF, 0xF, true);
    return p + __int_as_float(t);
}

// sum over the 32 lanes of this head; result in all lanes.
__device__ __forceinline__ float head_reduce(float p) {
    p = dpp_add<0xB1>(p);     // xor 1
    p = dpp_add<0x4E>(p);     // xor 2
    p = dpp_add<0x141>(p);    // xor 7 (half mirror)
    p = dpp_add<0x140>(p);    // xor 15 (row mirror)
    p += swz<0x401F>(p);      // xor 16
    return p;
}

// truncating fp32 -> (hi, lo) bf16 split
__device__ __forceinline__ short2 bsplit(float x) {
    unsigned u = __float_as_uint(x);
    short hi = (short)(u >> 16);
    float hif = __uint_as_float(u & 0xFFFF0000u);
    short lo = (short)(__float_as_uint(x - hif) >> 16);
    return make_short2(hi, lo);
}

// ---- setup: blocks 0,1 = bfrag (split-bf16 B fragments); block 2 = zeroing --
__global__ __launch_bounds__(512) void setup_kernel(const float* __restrict__ W1,
                                                    const float* __restrict__ Wm1,
                                                    short* __restrict__ BfW1,
                                                    short* __restrict__ BfWm,
                                                    int* __restrict__ bucket_base,
                                                    float* __restrict__ easum, int nbuck) {
    if (blockIdx.x == 2) {
        for (int i = threadIdx.x; i <= nbuck; i += 512) bucket_base[i] = 0;
        if (threadIdx.x < 2) easum[threadIdx.x] = 0.f;
        return;
    }
    int snt = threadIdx.x >> 6;
    int lane = threadIdx.x & 63;
    int s = snt >> 2, nt = snt & 3;
    int col = nt * 16 + (lane & 15);
    short* Bf = blockIdx.x == 0 ? BfW1 : BfWm;
#pragma unroll
    for (int j = 0; j < 8; ++j) {
        int k = s * 32 + (lane >> 4) * 8 + j;
        float v;
        if (blockIdx.x == 0) {
            v = W1[k * 64 + col];
        } else {
            v = (col < 32) ? Wm1[k * 32 + col] : Wm1[(64 + k) * 32 + (col - 32)];
        }
        short2 t = bsplit(v);
        Bf[(snt * 2 + 0) * 512 + lane * 8 + j] = t.x;
        Bf[(snt * 2 + 1) * 512 + lane * 8 + j] = t.y;
    }
}

// ---- pre: easum (block-tree + 2 atomics/block) fused with bucket histogram --
__global__ __launch_bounds__(256) void pre_kernel(const int* __restrict__ ei,
                                                  const float2* __restrict__ ea,
                                                  int* __restrict__ bucket_base,
                                                  float* __restrict__ easum,
                                                  int E, int EP, int nbuck) {
    extern __shared__ int lcnt[];
    __shared__ float r0[4], r1[4];
    int tid = threadIdx.x;
    for (int i = tid; i < nbuck; i += 256) lcnt[i] = 0;
    float s0 = 0.f, s1 = 0.f;
    int estride = gridDim.x * 256;
    for (int e = blockIdx.x * 256 + tid; e < E; e += estride) {
        float2 v = ea[e];
        s0 += v.x; s1 += v.y;
    }
#pragma unroll
    for (int o = 32; o >= 1; o >>= 1) {
        s0 += __shfl_xor(s0, o);
        s1 += __shfl_xor(s1, o);
    }
    int wave = tid >> 6;
    if ((tid & 63) == 0) { r0[wave] = s0; r1[wave] = s1; }
    __syncthreads();
    int base = blockIdx.x * CH;
    int end = min(base + CH, EP);
    for (int i = base + tid; i < end; i += 256) {
        int d = (i < E) ? ei[E + i] : (i - E);
        atomicAdd(&lcnt[d >> BSH], 1);
    }
    __syncthreads();
    if (tid == 0) {
        atomicAdd(&easum[0], r0[0] + r0[1] + r0[2] + r0[3]);
        atomicAdd(&easum[1], r1[0] + r1[1] + r1[2] + r1[3]);
    }
    for (int i = tid; i < nbuck; i += 256) {
        int c = lcnt[i];
        if (c) atomicAdd(&bucket_base[i], c);
    }
}

// single-block exclusive scan of bucket counts
__global__ __launch_bounds__(256) void bscan_kernel(int* __restrict__ bucket_base,
                                                    int* __restrict__ bucket_cursor,
                                                    int* __restrict__ row_ptr,
                                                    int N, int nbuck) {
    __shared__ int sm[256];
    int tid = threadIdx.x;
    int K = (nbuck + 255) / 256;
    int b0 = tid * K;
    int local = 0;
    for (int k = 0; k < K; ++k) {
        int b = b0 + k;
        if (b < nbuck) local += bucket_base[b];
    }
    sm[tid] = local;
    __syncthreads();
    for (int st = 1; st < 256; st <<= 1) {
        int v = sm[tid];
        int a = (tid >= st) ? sm[tid - st] : 0;
        __syncthreads();
        sm[tid] = v + a;
        __syncthreads();
    }
    int run = (tid == 0) ? 0 : sm[tid - 1];
    for (int k = 0; k < K; ++k) {
        int b = b0 + k;
        if (b < nbuck) {
            int c = bucket_base[b];
            bucket_base[b] = run;
            bucket_cursor[b] = run;
            run += c;
        }
    }
    if (tid == 255) {
        bucket_base[nbuck] = sm[255];
        row_ptr[N] = sm[255];
    }
}

// partition edges into bucket-contiguous staged[]; records {src, eax, eay, dst}
__global__ __launch_bounds__(256) void phaseA_kernel(const int* __restrict__ ei,
                                                     const float2* __restrict__ ea,
                                                     const float* __restrict__ easum,
                                                     int* __restrict__ bucket_cursor,
                                                     float4* __restrict__ staged,
                                                     int E, int EP, int nbuck) {
    extern __shared__ int sm[];          // lcnt[nbuck] then lbase[nbuck]
    int* lcnt = sm;
    int* lbase = sm + nbuck;
    int tid = threadIdx.x;
    for (int i = tid; i < nbuck; i += 256) lcnt[i] = 0;
    __syncthreads();
    int base = blockIdx.x * CH;
    int end = min(base + CH, EP);
    for (int i = base + tid; i < end; i += 256) {
        int d = (i < E) ? ei[E + i] : (i - E);
        atomicAdd(&lcnt[d >> BSH], 1);
    }
    __syncthreads();
    for (int i = tid; i < nbuck; i += 256) {
        int c = lcnt[i];
        lbase[i] = c ? atomicAdd(&bucket_cursor[i], c) : 0;
        lcnt[i] = 0;
    }
    __syncthreads();
    float inv = 1.f / (float)E;
    float m0 = easum[0] * inv, m1 = easum[1] * inv;
    for (int i = base + tid; i < end; i += 256) {
        int s, d; float ex, ey;
        if (i < E) {
            s = ei[i]; d = ei[E + i];
            float2 v = ea[i]; ex = v.x; ey = v.y;
        } else {
            s = d = i - E; ex = m0; ey = m1;
        }
        int b = d >> BSH;
        int pos = lbase[b] + atomicAdd(&lcnt[b], 1);
        staged[pos] = make_float4(__int_as_float(s), ex, ey, __int_as_float(d));
    }
}

// per bucket: per-node LDS count + scan -> row_ptr; exact CSR placement
__global__ __launch_bounds__(256) void phaseB_kernel(const float4* __restrict__ staged,
                                                     const int* __restrict__ bucket_base,
                                                     int* __restrict__ row_ptr,
                                                     float4* __restrict__ recs, int N) {
    __shared__ int cnt128[128];
    __shared__ int offs[128];
    int b = blockIdx.x;
    int n0 = b << BSH;
    int tid = threadIdx.x;
    if (tid < 128) cnt128[tid] = 0;
    __syncthreads();
    int begs = bucket_base[b];
    int ends = bucket_base[b + 1];
    for (int i = begs + tid; i < ends; i += 256) {
        int d = __float_as_int(staged[i].w);
        atomicAdd(&cnt128[d - n0], 1);
    }
    __syncthreads();
    if (tid < 128) offs[tid] = cnt128[tid];
    __syncthreads();
    for (int st = 1; st < 128; st <<= 1) {
        int v = 0;
        if (tid < 128) {
            v = offs[tid];
            if (tid >= st) v += offs[tid - st];
        }
        __syncthreads();
        if (tid < 128) offs[tid] = v;
        __syncthreads();
    }
    if (tid < 128) {
        int excl = begs + offs[tid] - cnt128[tid];
        int node = n0 + tid;
        if (node < N) row_ptr[node] = excl;
        offs[tid] = excl;
    }
    __syncthreads();
    for (int i = begs + tid; i < ends; i += 256) {
        float4 r = staged[i];
        int d = __float_as_int(r.w);
        int pos = atomicAdd(&offs[d - n0], 1);
        recs[pos] = r;
    }
}

// ---- wgt0: edge-parallel layer-0 attention weights --------------------------
__global__ __launch_bounds__(256) void wgt0_kernel(const float2* __restrict__ x,
                                                   const float* __restrict__ W0,
                                                   const float* __restrict__ b0,
                                                   const float4* __restrict__ recs,
                                                   const float* __restrict__ We,
                                                   const float* __restrict__ att,
                                                   float4* __restrict__ wrec, int EP) {
    int lane = threadIdx.x & 63;
    int m = lane & 15, quad = lane >> 4;
    int c0 = quad * 8, c1 = 32 + c0;
    float w0a[8], w1a[8], ata[8], w0b[8], w1b[8], atb[8];
    float Wxa[8], Wya[8], bca[8], Wxb[8], Wyb[8], bcb[8];
#pragma unroll
    for (int j = 0; j < 8; ++j) {
        w0a[j] = We[c0 + j];  w1a[j] = We[64 + c0 + j];  ata[j] = att[c0 + j];
        w0b[j] = We[c1 + j];  w1b[j] = We[64 + c1 + j];  atb[j] = att[c1 + j];
        Wxa[j] = W0[c0 + j];  Wya[j] = W0[64 + c0 + j];  bca[j] = b0[c0 + j];
        Wxb[j] = W0[c1 + j];  Wyb[j] = W0[64 + c1 + j];  bcb[j] = b0[c1 + j];
    }
    int ntiles = (EP + 15) >> 4;
    int wid = (blockIdx.x * blockDim.x + threadIdx.x) >> 6;
    int nw = (gridDim.x * blockDim.x) >> 6;
    for (int t = wid; t < ntiles; t += nw) {
        int e = t * 16 + m;
        int ec = e < EP ? e : EP - 1;
        float4 r = recs[ec];
        int s = __float_as_int(r.x);
        int d = __float_as_int(r.w);
        float2 xs = x[s];
        float2 xd = x[d];
        float P0 = 0.f, P1 = 0.f;
#pragma unroll
        for (int j = 0; j < 8; ++j) {
            float zs = fmaf(xs.x, Wxa[j], fmaf(xs.y, Wya[j], bca[j]));
            float zd = fmaf(xd.x, Wxa[j], fmaf(xd.y, Wya[j], bca[j]));
            float t0 = zd + zs + fmaf(r.y, w0a[j], r.z * w1a[j]);
            t0 = fmaxf(t0, 0.2f * t0);
            P0 = fmaf(t0, ata[j], P0);
            float zs1 = fmaf(xs.x, Wxb[j], fmaf(xs.y, Wyb[j], bcb[j]));
            float zd1 = fmaf(xd.x, Wxb[j], fmaf(xd.y, Wyb[j], bcb[j]));
            float t1 = zd1 + zs1 + fmaf(r.y, w0b[j], r.z * w1b[j]);
            t1 = fmaxf(t1, 0.2f * t1);
            P1 = fmaf(t1, atb[j], P1);
        }
        P0 += swz<0x401F>(P0);             // quad pair (xor 16)
        P1 += swz<0x401F>(P1);
        P0 += __shfl_xor(P0, 32);          // cross-half (xor 32)
        P1 += __shfl_xor(P1, 32);
        float w0 = __expf(fminf(P0, 60.f));
        float w1 = __expf(fminf(P1, 60.f));
        if (lane < 16 && e < EP) wrec[e] = make_float4(w0, w1, xs.x, xs.y);
    }
}

// ---- hagg0: wave/node, lanes=EDGES; stream wrec; 6-scalar butterfly ---------
__global__ __launch_bounds__(256) void hagg0_kernel(const float4* __restrict__ wrec,
                                                    const int* __restrict__ row_ptr,
                                                    const float* __restrict__ W0,
                                                    const float* __restrict__ b0,
                                                    const float* __restrict__ bias,
                                                    float* __restrict__ hout, int N) {
    int gtid = blockIdx.x * blockDim.x + threadIdx.x;
    int n = gtid >> 6;
    if (n >= N) return;
    n = __builtin_amdgcn_readfirstlane(n);
    int lane = threadIdx.x & 63;
    int beg = row_ptr[n], end = row_ptr[n + 1];
    float a0 = 0.f, a1 = 0.f, a2 = 0.f, c0 = 0.f, c1 = 0.f, c2 = 0.f;
    for (int i = beg + lane; i < end; i += 64) {
        float4 r = wrec[i];
        a0 += r.x; a1 = fmaf(r.x, r.z, a1); a2 = fmaf(r.x, r.w, a2);
        c0 += r.y; c1 = fmaf(r.y, r.z, c1); c2 = fmaf(r.y, r.w, c2);
    }
#pragma unroll
    for (int o = 32; o >= 1; o >>= 1) {
        a0 += __shfl_xor(a0, o); a1 += __shfl_xor(a1, o); a2 += __shfl_xor(a2, o);
        c0 += __shfl_xor(c0, o); c1 += __shfl_xor(c1, o); c2 += __shfl_xor(c2, o);
    }
    int head = lane >> 5;
    float l  = head ? c0 : a0;
    float Sx = head ? c1 : a1;
    float Sy = head ? c2 : a2;
    float num = fmaf(W0[lane], Sx, fmaf(W0[64 + lane], Sy, b0[lane] * l));
    float v = num / (l + 1e-16f) + bias[lane];
    v = (v > 0.f) ? v : expm1f(v);       // ELU
    hout[(size_t)n * 64 + lane] = v;
}

// ---- agg1: fused attention+aggregation, layer 1; z stored FP16 --------------
__global__ __launch_bounds__(256) void agg1_kernel(
    const __half* __restrict__ z, const int* __restrict__ row_ptr,
    const float4* __restrict__ recs,
    const float* __restrict__ We, const float* __restrict__ att,
    const float* __restrict__ bias, float* __restrict__ hout, int N) {
    int gtid = blockIdx.x * blockDim.x + threadIdx.x;
    int n = gtid >> 6;
    if (n >= N) return;
    n = __builtin_amdgcn_readfirstlane(n);
    int lane = threadIdx.x & 63;

    float We0 = We[lane], We1 = We[64 + lane];
    float attj = att[lane];
    float zn = __half2float(z[(size_t)n * 64 + lane]);

    int beg = row_ptr[n], end = row_ptr[n + 1];
    float ll[4] = {0.f, 0.f, 0.f, 0.f};
    float aa[4] = {0.f, 0.f, 0.f, 0.f};
    int i = beg;
    for (; i + 8 <= end; i += 8) {
        float w[8], zs[8];
#pragma unroll
        for (int k = 0; k < 8; ++k) {
            float4 r = recs[i + k];
            int s = __builtin_amdgcn_readfirstlane(__float_as_int(r.x));
            float zv = __half2float(z[(size_t)s * 64 + lane]);
            float sj = zn + zv + fmaf(r.y, We0, r.z * We1);
            sj = fmaxf(sj, 0.2f * sj);
            float alpha = head_reduce(sj * attj);
            w[k] = __expf(fminf(alpha, 60.f));
            zs[k] = zv;
        }
#pragma unroll
        for (int k = 0; k < 8; ++k) {
            ll[k & 3] += w[k];
            aa[k & 3] = fmaf(w[k], zs[k], aa[k & 3]);
        }
    }
    for (; i < end; ++i) {
        float4 r = recs[i];
        int s = __builtin_amdgcn_readfirstlane(__float_as_int(r.x));
        float zv = __half2float(z[(size_t)s * 64 + lane]);
        float sj = zn + zv + fmaf(r.y, We0, r.z * We1);
        sj = fmaxf(sj, 0.2f * sj);
        float alpha = head_reduce(sj * attj);
        float w = __expf(fminf(alpha, 60.f));
        ll[0] += w;
        aa[0] = fmaf(w, zv, aa[0]);
    }
    float l = (ll[0] + ll[1]) + (ll[2] + ll[3]);
    float a = (aa[0] + aa[1]) + (aa[2] + aa[3]);
    float v = a / (l + 1e-16f) + bias[lane];
    v = (v > 0.f) ? v : expm1f(v);
    hout[(size_t)n * 64 + lane] = v;
}

// ---- out[N x 64] = h[N x 64] @ B[64 x 64] (+ bias), split-bf16 MFMA ---------
// FP16 output (consumed by random-gather kernels: halves their HBM traffic).
// optional gvec fold: block 0 threads 0-31 also compute the goal vector.
__global__ __launch_bounds__(256) void mfma_gemm64(const float* __restrict__ h,
                                                   const short* __restrict__ Bf,
                                                   const float* __restrict__ bias,
                                                   __half* __restrict__ out, int N,
                                                   const float* __restrict__ Wm1,
                                                   const float* __restrict__ bm1,
                                                   const int* __restrict__ dest,
                                                   float* __restrict__ gv) {
    int wave = threadIdx.x >> 6;
    int lane = threadIdx.x & 63;
    int n0 = blockIdx.x * 64 + wave * 16;
    if (n0 < N) {
        int m = lane & 15, quad = lane >> 4;
        int arow = n0 + m;
        if (arow > N - 1) arow = N - 1;
        f32x4 acc[4] = {{0.f, 0.f, 0.f, 0.f}, {0.f, 0.f, 0.f, 0.f},
                        {0.f, 0.f, 0.f, 0.f}, {0.f, 0.f, 0.f, 0.f}};
#pragma unroll
        for (int s = 0; s < 2; ++s) {
            const float* ap = h + (size_t)arow * 64 + s * 32 + quad * 8;
            float4 a0 = *(const float4*)ap;
            float4 a1 = *(const float4*)(ap + 4);
            short8 ahi, alo;
            short2 t;
            t = bsplit(a0.x); ahi[0] = t.x; alo[0] = t.y;
            t = bsplit(a0.y); ahi[1] = t.x; alo[1] = t.y;
            t = bsplit(a0.z); ahi[2] = t.x; alo[2] = t.y;
            t = bsplit(a0.w); ahi[3] = t.x; alo[3] = t.y;
            t = bsplit(a1.x); ahi[4] = t.x; alo[4] = t.y;
            t = bsplit(a1.y); ahi[5] = t.x; alo[5] = t.y;
            t = bsplit(a1.z); ahi[6] = t.x; alo[6] = t.y;
            t = bsplit(a1.w); ahi[7] = t.x; alo[7] = t.y;
#pragma unroll
            for (int nt = 0; nt < 4; ++nt) {
                const short* bp = Bf + ((s * 4 + nt) * 2) * 512 + lane * 8;
                short8 bhi = *(const short8*)bp;
                short8 blo = *(const short8*)(bp + 512);
                acc[nt] = __builtin_amdgcn_mfma_f32_16x16x32_bf16(ahi, bhi, acc[nt], 0, 0, 0);
                acc[nt] = __builtin_amdgcn_mfma_f32_16x16x32_bf16(ahi, blo, acc[nt], 0, 0, 0);
                acc[nt] = __builtin_amdgcn_mfma_f32_16x16x32_bf16(alo, bhi, acc[nt], 0, 0, 0);
            }
        }
#pragma unroll
        for (int nt = 0; nt < 4; ++nt) {
            int col = nt * 16 + m;
            float bj = bias ? bias[col] : 0.f;
#pragma unroll
            for (int r = 0; r < 4; ++r) {
                int orow = n0 + quad * 4 + r;
                if (orow < N) out[(size_t)orow * 64 + col] = __float2half(acc[nt][r] + bj);
            }
        }
    }
    if (gv && blockIdx.x == 0 && threadIdx.x < 32) {
        int dd = dest[0];
        int q = threadIdx.x;
        float acc2 = bm1[q];
        for (int k = 0; k < 64; ++k)
            acc2 = fmaf(h[(size_t)dd * 64 + k], Wm1[(128 + k) * 32 + q], acc2);
        gv[q] = acc2;
    }
}

// 8 lanes per edge; hsd FP16: [n*64+0:32]=hs, [n*64+32:64]=hd
__global__ __launch_bounds__(256) void edge_mlp_kernel(
    const int* __restrict__ ei, const float2* __restrict__ ea,
    const __half* __restrict__ hsd, const float* __restrict__ gvec,
    const float* __restrict__ WrowA, const float* __restrict__ WrowB,
    const float* __restrict__ Wm2, const float* __restrict__ bm2,
    float* __restrict__ out, int E) {
    int tid = blockIdx.x * blockDim.x + threadIdx.x;
    int e = tid >> 3;
    int j = tid & 7;
    if (e >= E) return;
    int s = ei[e], d = ei[E + e];
    float2 eav = ea[e];
    const __half2* ps = (const __half2*)(hsd + (size_t)s * 64 + j * 4);
    const __half2* pd = (const __half2*)(hsd + (size_t)d * 64 + 32 + j * 4);
    float2 a01 = __half22float2(ps[0]), a23 = __half22float2(ps[1]);
    float2 b01 = __half22float2(pd[0]), b23 = __half22float2(pd[1]);
    float4 g = *(const float4*)(gvec + j * 4);
    float4 wa = *(const float4*)(WrowA + j * 4);
    float4 wb = *(const float4*)(WrowB + j * 4);
    float4 w2 = *(const float4*)(Wm2 + j * 4);
    float acc = 0.f, v;
    v = fmaf(eav.x, wa.x, fmaf(eav.y, wb.x, a01.x + b01.x + g.x)); v = fmaxf(v, 0.f); acc = fmaf(v, w2.x, acc);
    v = fmaf(eav.x, wa.y, fmaf(eav.y, wb.y, a01.y + b01.y + g.y)); v = fmaxf(v, 0.f); acc = fmaf(v, w2.y, acc);
    v = fmaf(eav.x, wa.z, fmaf(eav.y, wb.z, a23.x + b23.x + g.z)); v = fmaxf(v, 0.f); acc = fmaf(v, w2.z, acc);
    v = fmaf(eav.x, wa.w, fmaf(eav.y, wb.w, a23.y + b23.y + g.w)); v = fmaxf(v, 0.f); acc = fmaf(v, w2.w, acc);
    acc = dpp_add<0xB1>(acc);
    acc = dpp_add<0x4E>(acc);
    acc = dpp_add<0x141>(acc);
    if (j == 0) out[e] = acc + bm2[0];
}

extern "C" void kernel_launch(void* const* d_in, const int* in_sizes, int n_in,
                              void* d_out, int out_size, void* d_ws, size_t ws_size,
                              hipStream_t stream) {
    const float* x     = (const float*)d_in[0];
    const int*   ei    = (const int*)d_in[1];
    const float* ea    = (const float*)d_in[2];
    const int*   dest  = (const int*)d_in[3];
    const float* W0    = (const float*)d_in[4];
    const float* b0    = (const float*)d_in[5];
    const float* We0   = (const float*)d_in[6];
    const float* att0  = (const float*)d_in[7];
    const float* bias0 = (const float*)d_in[8];
    const float* W1    = (const float*)d_in[9];
    const float* b1    = (const float*)d_in[10];
    const float* We1   = (const float*)d_in[11];
    const float* att1  = (const float*)d_in[12];
    const float* bias1 = (const float*)d_in[13];
    const float* Wm1   = (const float*)d_in[14];
    const float* bm1   = (const float*)d_in[15];
    const float* Wm2   = (const float*)d_in[16];
    const float* bm2   = (const float*)d_in[17];

    const int N = in_sizes[0] / 2;
    const int E = in_sizes[1] / 2;
    const int EP = E + N;
    const int nbuck = (N + 127) >> BSH;
    const int nchunk = (EP + CH - 1) / CH;

    char* ws = (char*)d_ws;
    size_t off = 0;
    auto alloc = [&](size_t bytes) -> void* {
        void* p = ws + off;
        off += bytes;
        off = (off + 255) & ~(size_t)255;
        return p;
    };
    int*    bucket_base   = (int*)alloc((size_t)(nbuck + 1) * 4);
    int*    bucket_cursor = (int*)alloc((size_t)nbuck * 4);
    int*    row_ptr       = (int*)alloc((size_t)(N + 1) * 4);
    size_t  shared_bytes  = (size_t)EP * 16 > (size_t)N * 128 ? (size_t)EP * 16
                                                              : (size_t)N * 128;
    float4* staged        = (float4*)alloc(shared_bytes);   // also z16/hsd16 (N*64*2B)
    float4* recs          = (float4*)alloc((size_t)EP * 16);
    float4* wrec          = (float4*)alloc((size_t)EP * 16);
    float*  hbuf          = (float*)alloc((size_t)N * 64 * 4);
    float*  easum         = (float*)alloc(8);
    float*  gvec          = (float*)alloc(32 * 4);
    short*  BfW1          = (short*)alloc(8192 * 2);
    short*  BfWm          = (short*)alloc(8192 * 2);
    __half* z16           = (__half*)staged;  // staged dead before gemm writes
    __half* hsd16         = z16;              // z1 dead after layer-1 agg

    dim3 blk(256);
    setup_kernel<<<3, 512, 0, stream>>>(W1, Wm1, BfW1, BfWm, bucket_base, easum, nbuck);
    pre_kernel<<<nchunk, blk, (size_t)nbuck * 4, stream>>>(ei, (const float2*)ea,
                                                           bucket_base, easum, E, EP, nbuck);
    bscan_kernel<<<1, blk, 0, stream>>>(bucket_base, bucket_cursor, row_ptr, N, nbuck);
    phaseA_kernel<<<nchunk, blk, (size_t)nbuck * 8, stream>>>(ei, (const float2*)ea, easum,
                                                              bucket_cursor, staged, E, EP, nbuck);
    phaseB_kernel<<<nbuck, blk, 0, stream>>>(staged, bucket_base, row_ptr, recs, N);
    wgt0_kernel<<<2048, blk, 0, stream>>>((const float2*)x, W0, b0, recs, We0, att0, wrec, EP);
    hagg0_kernel<<<(N * 64 + 255) / 256, blk, 0, stream>>>(wrec, row_ptr, W0, b0,
                                                           bias0, hbuf, N);
    mfma_gemm64<<<(N + 63) / 64, blk, 0, stream>>>(hbuf, BfW1, b1, z16, N,
                                                   nullptr, nullptr, nullptr, nullptr);
    agg1_kernel<<<(N * 64 + 255) / 256, blk, 0, stream>>>(z16, row_ptr, recs,
                                                          We1, att1, bias1, hbuf, N);
    mfma_gemm64<<<(N + 63) / 64, blk, 0, stream>>>(hbuf, BfWm, (const float*)nullptr, hsd16, N,
                                                   Wm1, bm1, dest, gvec);
    edge_mlp_kernel<<<((size_t)E * 8 + 255) / 256, blk, 0, stream>>>(
        ei, (const float2*)ea, hsd16, gvec,
        Wm1 + 192 * 32, Wm1 + 193 * 32, Wm2, bm2, (float*)d_out, E);
}